// Round 12
// baseline (454.762 us; speedup 1.0000x reference)
//
#include <hip/hip_runtime.h>
#include <hip/hip_bf16.h>
#include <math.h>
#include <type_traits>

typedef __bf16 v8bf __attribute__((ext_vector_type(8)));
typedef __bf16 v4bf __attribute__((ext_vector_type(4)));
typedef float  v4f  __attribute__((ext_vector_type(4)));

__device__ __forceinline__ float wave_reduce_sum(float v) {
#pragma unroll
    for (int m = 1; m < 64; m <<= 1) v += __shfl_xor(v, m, 64);
    return v;
}

__device__ __forceinline__ unsigned fenc(float x) {
    unsigned u = __float_as_uint(x);
    return (u & 0x80000000u) ? ~u : (u | 0x80000000u);
}
__device__ __forceinline__ float fdec(unsigned k) {
    return (k & 0x80000000u) ? __uint_as_float(k ^ 0x80000000u) : __uint_as_float(~k);
}

__device__ __forceinline__ void gload16(const void* g, void* l) {
    __builtin_amdgcn_global_load_lds((const __attribute__((address_space(1))) void*)g,
                                     (__attribute__((address_space(3))) void*)l, 16, 0, 0);
}

// ---------------- conversion kernels ----------------

__global__ __launch_bounds__(256) void cvt_f32_bf16(const float* __restrict__ in,
                                                    __bf16* __restrict__ out, long long n) {
    long long i = ((long long)blockIdx.x * 256 + threadIdx.x) * 4;
    if (i >= n) return;
    v4f v = *(const v4f*)(in + i);
    v4bf o;
    o[0] = (__bf16)v[0]; o[1] = (__bf16)v[1]; o[2] = (__bf16)v[2]; o[3] = (__bf16)v[3];
    *(v4bf*)(out + i) = o;
}

// Router grid (small latency-bound work FIRST so it hides under the stream):
//   blocks [0,256): beta (bs = b_sbj + b_rel@Ws_r ; bo = b_obj + b_rel@Wo_r)
//   blocks [256, 256+6*perz): six transpose-convert slices (32x32 tiles)
//   blocks [256+6*perz, ...): relv copy+cvt | W_rel cvt | V cvt, 8 floats/thread,
//                             non-temporal stores for write-once data
__global__ __launch_bounds__(256) void megacvt(
    const float* __restrict__ relv, float* __restrict__ outCopy, __bf16* __restrict__ relv_b,
    long long nr,
    const float* __restrict__ wrel, __bf16* __restrict__ wrel_b, long long nw,
    const float* __restrict__ vsrc, __bf16* __restrict__ v_b, long long nv,
    const float* __restrict__ b_rel, const float* __restrict__ b_sbj, const float* __restrict__ b_obj,
    const float* __restrict__ Wsr, const float* __restrict__ Wor,
    float* __restrict__ bs, float* __restrict__ bo, int D, int Nn,
    __bf16* __restrict__ WoWs_T, __bf16* __restrict__ Ws_vT, __bf16* __restrict__ Wo_vT,
    __bf16* __restrict__ VbT, const float* __restrict__ W_ctx, __bf16* __restrict__ W_ctxT) {
    __shared__ float tile[32][33];
    const int perz = (D / 32) * (D / 32);
    const long long blk = blockIdx.x;
    const size_t DDl = (size_t)D * D;

    if (blk < 256) {
        // beta: 2-stage bias projection, coalesced row-major reads, atomicAdd partials
        int bb = (int)blk;
        const int col = (bb & 3) * 256 + threadIdx.x;
        const int chunk = (bb >> 2) & 31;
        const int mat = bb >> 7;
        const int rpc = D / 32;
        const int r0 = chunk * rpc;
        const float* W = (mat == 0) ? Wsr : Wor;
        float acc = 0.f;
        if (chunk == 0) acc = (mat == 0) ? b_sbj[col] : b_obj[col];
        for (int r = r0; r < r0 + rpc; ++r)
            acc += b_rel[r] * W[(size_t)r * D + col];
        atomicAdd(((mat == 0) ? bs : bo) + col, acc);
        return;
    }
    if (blk < 256 + 6LL * perz) {
        int tb = (int)(blk - 256);
        int z = tb / perz, rem = tb % perz;
        const float* ins[6];
        __bf16* outs[6];
        int Rs[6];
        ins[0] = Wor;        outs[0] = WoWs_T;       Rs[0] = D;   // Wo_r^T
        ins[1] = Wsr;        outs[1] = WoWs_T + DDl; Rs[1] = D;   // Ws_r^T
        ins[2] = Wsr - DDl;  outs[2] = Ws_vT;        Rs[2] = D;   // Ws_v^T (= W_sbj[:D])
        ins[3] = Wor - DDl;  outs[3] = Wo_vT;        Rs[3] = D;   // Wo_v^T (= W_obj[:D])
        ins[4] = vsrc;       outs[4] = VbT;          Rs[4] = Nn;  // V^T
        ins[5] = W_ctx;      outs[5] = W_ctxT;       Rs[5] = D;   // W_ctx^T
        const float* in = ins[z];
        __bf16* out = outs[z];
        const int R = Rs[z], C = D;
        int cb = (rem % (D / 32)) * 32, rb = (rem / (D / 32)) * 32;
        if (cb >= C || rb >= R) return;
        int tx = threadIdx.x & 31, ty = threadIdx.x >> 5;
#pragma unroll
        for (int i = 0; i < 32; i += 8)
            tile[ty + i][tx] = in[(size_t)(rb + ty + i) * C + cb + tx];
        __syncthreads();
#pragma unroll
        for (int i = 0; i < 32; i += 8)
            out[(size_t)(cb + ty + i) * R + rb + tx] = (__bf16)tile[tx][ty + i];
        return;
    }
    // stream: 8 floats per thread
    long long i = ((blk - 256 - 6LL * perz) * 256 + threadIdx.x) * 8;
    if (i < nr) {
        v4f a = *(const v4f*)(relv + i);
        v4f b = *(const v4f*)(relv + i + 4);
        __builtin_nontemporal_store(a, (v4f*)(outCopy + i));
        __builtin_nontemporal_store(b, (v4f*)(outCopy + i + 4));
        v8bf o;
        o[0] = (__bf16)a[0]; o[1] = (__bf16)a[1]; o[2] = (__bf16)a[2]; o[3] = (__bf16)a[3];
        o[4] = (__bf16)b[0]; o[5] = (__bf16)b[1]; o[6] = (__bf16)b[2]; o[7] = (__bf16)b[3];
        __builtin_nontemporal_store(o, (v8bf*)(relv_b + i));
    } else if (i < nr + nw) {
        long long j = i - nr;
        v4f a = *(const v4f*)(wrel + j);
        v4f b = *(const v4f*)(wrel + j + 4);
        v8bf o;
        o[0] = (__bf16)a[0]; o[1] = (__bf16)a[1]; o[2] = (__bf16)a[2]; o[3] = (__bf16)a[3];
        o[4] = (__bf16)b[0]; o[5] = (__bf16)b[1]; o[6] = (__bf16)b[2]; o[7] = (__bf16)b[3];
        *(v8bf*)(wrel_b + j) = o;
    } else if (i < nr + nw + nv) {
        long long j = i - nr - nw;
        v4f a = *(const v4f*)(vsrc + j);
        v4f b = *(const v4f*)(vsrc + j + 4);
        v8bf o;
        o[0] = (__bf16)a[0]; o[1] = (__bf16)a[1]; o[2] = (__bf16)a[2]; o[3] = (__bf16)a[3];
        o[4] = (__bf16)b[0]; o[5] = (__bf16)b[1]; o[6] = (__bf16)b[2]; o[7] = (__bf16)b[3];
        *(v8bf*)(v_b + j) = o;
    }
}

// ---- bf16 MFMA GEMM, m97 structure + XOR-swizzled LDS ----
// MODE 0: outB (bf16, plain, ldOut) = acc (+addMat f32 [ldAdd] if non-null)
// MODE 3: fused logits partial (flat grid + chunked XCD swizzle)
// MODE 4: outF[m][n] = addMat[m][n] + (maskRow[m] ? acc + addRow[n] : 0)
// MODE 5: merged W-side: m-blocks 0-1 -> MT quadrants; m-block 2 -> KoKs.
template <int MODE, bool BIG>
__global__ __launch_bounds__(256, 5) void gemm_gl(
    const __bf16* __restrict__ Ap, int ldA,
    const __bf16* __restrict__ Btp, int ldB,
    int M, int N, int K,
    const float* __restrict__ addMat, int ldAdd,
    float* __restrict__ outF,
    __bf16* __restrict__ outB, int ldOut,
    __bf16* __restrict__ outB2,
    const __bf16* __restrict__ rbDot,
    float* __restrict__ qOut,
    const float* __restrict__ addRow,
    const int* __restrict__ maskRow,
    const int* __restrict__ sbjI,
    const int* __restrict__ objI,
    const __bf16* __restrict__ auxW) {
    constexpr int BM = BIG ? 128 : 64;
    constexpr int BN = BIG ? 128 : 64;
    constexpr int WM = BM / 2, WN = BN / 2;
    constexpr int FI = WM / 16, FJ = WN / 16;
    constexpr int NLA = (BM * 64) / 2048;
    constexpr int NLB = (BN * 64) / 2048;

    __shared__ alignas(16) __bf16 As[BM * 64];
    __shared__ alignas(16) __bf16 Bs[BN * 64];

    int m0, n0;
    if constexpr (MODE == 3) {
        // flat grid, chunked XCD swizzle: id%8 = mb%8 (panel pinned to one XCD);
        // the panel's 8 n-blocks are 8 ids apart -> temporally adjacent -> L2 reuse.
        const int id = blockIdx.x;
        const int mb = (id >> 6) * 8 + (id & 7);
        const int nb = (id >> 3) & 7;
        m0 = mb * BM;
        n0 = nb * BN;
    } else {
        m0 = blockIdx.x * BM;
        n0 = blockIdx.y * BN;
    }
    bool kRows = false;
    if constexpr (MODE == 5) {
        if (m0 >= 2048) {  // KoKs rows: A = Wr_r (= Btp + 2*K*K), Bt = WoWs_T (= Ap)
            kRows = true;
            const __bf16* t = Ap;
            Ap = Btp + (size_t)2 * K * K;
            Btp = t;
            m0 -= 2048;
        }
    }

    const int t = threadIdx.x, lane = t & 63, wid = t >> 6;
    const int wm = wid >> 1, wn = wid & 1;
    const int rA = t >> 3;
    const int cSw = (t & 7) ^ (rA & 7);            // swizzled 16B-chunk (involution)

    v4f acc[FI][FJ] = {};

    const int l15 = lane & 15;
    const int xorMask = (l15 & 7) << 4;            // read-side XOR (bytes)

    for (int kt = 0; kt < K; kt += 64) {
#pragma unroll
        for (int i = 0; i < NLA; ++i)
            gload16(Ap + (size_t)(m0 + i * 32 + rA) * ldA + kt + cSw * 8,
                    (char*)As + i * 4096 + wid * 1024);
#pragma unroll
        for (int i = 0; i < NLB; ++i)
            gload16(Btp + (size_t)(n0 + i * 32 + rA) * ldB + kt + cSw * 8,
                    (char*)Bs + i * 4096 + wid * 1024);
        __syncthreads();
#pragma unroll
        for (int ks = 0; ks < 2; ++ks) {
            const int kb = (ks * 64 + ((lane >> 4) << 4)) ^ xorMask;
            v8bf af[FI], bfr[FJ];
#pragma unroll
            for (int f = 0; f < FI; ++f)
                af[f] = *(const v8bf*)((const char*)As + (wm * WM + f * 16 + l15) * 128 + kb);
#pragma unroll
            for (int f = 0; f < FJ; ++f)
                bfr[f] = *(const v8bf*)((const char*)Bs + (wn * WN + f * 16 + l15) * 128 + kb);
#pragma unroll
            for (int i = 0; i < FI; ++i)
#pragma unroll
                for (int j = 0; j < FJ; ++j)
                    acc[i][j] = __builtin_amdgcn_mfma_f32_16x16x32_bf16(af[i], bfr[j], acc[i][j], 0, 0, 0);
        }
        __syncthreads();
    }

    const int cc = lane & 15, r4 = (lane >> 4) << 2;
    if constexpr (MODE == 3) {
#pragma unroll
        for (int i = 0; i < FI; ++i)
#pragma unroll
            for (int r = 0; r < 4; ++r) {
                const int gm = m0 + wm * WM + i * 16 + r4 + r;
                const int s = sbjI[gm], o = objI[gm];
                const float* Ps = addMat + (size_t)s * ldAdd;
                const float* Qo = outF + (size_t)o * ldAdd;
                float p = 0.f;
#pragma unroll
                for (int j = 0; j < FJ; ++j) {
                    const int gn = n0 + wn * WN + j * 16 + cc;
                    float rv = (float)rbDot[(size_t)gm * N + gn];
                    p += rv * (acc[i][j][r] + Ps[gn] + Qo[gn] + addRow[gn]);
                }
                p += __shfl_xor(p, 1, 64);
                p += __shfl_xor(p, 2, 64);
                p += __shfl_xor(p, 4, 64);
                p += __shfl_xor(p, 8, 64);
                if (cc == 0) atomicAdd(qOut + gm, p);
            }
    } else if constexpr (MODE == 5) {
        if (kRows) {
#pragma unroll
            for (int i = 0; i < FI; ++i)
#pragma unroll
                for (int j = 0; j < FJ; ++j)
#pragma unroll
                    for (int r = 0; r < 4; ++r) {
                        const int gm = m0 + wm * WM + i * 16 + r4 + r;
                        const int gn = n0 + wn * WN + j * 16 + cc;
                        outB2[(size_t)gm * 2048 + gn] = (__bf16)acc[i][j][r];
                    }
        } else {
            const int mb = m0 >> 10, nb = n0 >> 10;
            const int blk = (mb == 0) ? (nb ? 3 : 1) : (nb ? 2 : 0);
            const __bf16* addB = (blk == 0) ? rbDot : (blk == 3 ? auxW : nullptr);
            const size_t DDe = (size_t)ldOut * ldOut;
            __bf16* dst = outB + (size_t)blk * DDe;
#pragma unroll
            for (int i = 0; i < FI; ++i)
#pragma unroll
                for (int j = 0; j < FJ; ++j)
#pragma unroll
                    for (int r = 0; r < 4; ++r) {
                        const int gml = (m0 + wm * WM + i * 16 + r4 + r) & 1023;
                        const int gnl = (n0 + wn * WN + j * 16 + cc) & 1023;
                        float v = acc[i][j][r];
                        if (addB) v += (float)addB[(size_t)gml * ldOut + gnl];
                        dst[(size_t)gml * ldOut + gnl] = (__bf16)v;
                    }
        }
    } else {
#pragma unroll
        for (int i = 0; i < FI; ++i)
#pragma unroll
            for (int j = 0; j < FJ; ++j)
#pragma unroll
                for (int r = 0; r < 4; ++r) {
                    const int gm = m0 + wm * WM + i * 16 + r4 + r;
                    const int gn = n0 + wn * WN + j * 16 + cc;
                    float v = acc[i][j][r];
                    if constexpr (MODE == 0) {
                        if (addMat) v += addMat[(size_t)gm * ldAdd + gn];
                        outB[(size_t)gm * ldOut + gn] = (__bf16)v;
                    } else {  // MODE 4
                        float u = addMat[(size_t)gm * ldAdd + gn];
                        if (maskRow[gm]) u += v + addRow[gn];
                        outF[(size_t)gm * ldOut + gn] = u;
                    }
                }
    }
}

// ---- batched pair at 128² tiles: z=0 ZT = Ko@Ks^T ; z=1 ACBD = Vb@MT_all^T ----
__global__ __launch_bounds__(256, 5) void gemm128_pair(
    const __bf16* __restrict__ A0, int ldA0, const __bf16* __restrict__ B0, int ldB0,
    int M0v, int N0v, __bf16* __restrict__ O0, int ldO0,
    const __bf16* __restrict__ A1, int ldA1, const __bf16* __restrict__ B1, int ldB1,
    int M1v, int N1v, __bf16* __restrict__ O1, int ldO1, int K) {
    const __bf16* Ap; const __bf16* Btp; __bf16* Ob;
    int ldA, ldB, Mv, Nv, ldO;
    if (blockIdx.z == 0) { Ap = A0; Btp = B0; Ob = O0; ldA = ldA0; ldB = ldB0; Mv = M0v; Nv = N0v; ldO = ldO0; }
    else                 { Ap = A1; Btp = B1; Ob = O1; ldA = ldA1; ldB = ldB1; Mv = M1v; Nv = N1v; ldO = ldO1; }
    const int m0 = blockIdx.x * 128, n0 = blockIdx.y * 128;
    if (m0 >= Mv || n0 >= Nv) return;

    __shared__ alignas(16) __bf16 As[128 * 64];
    __shared__ alignas(16) __bf16 Bs[128 * 64];
    const int t = threadIdx.x, lane = t & 63, wid = t >> 6;
    const int wm = wid >> 1, wn = wid & 1;
    const int rA = t >> 3;
    const int cSw = (t & 7) ^ (rA & 7);
    const int l15 = lane & 15;
    const int xorMask = (l15 & 7) << 4;
    v4f acc[4][4] = {};

    for (int kt = 0; kt < K; kt += 64) {
#pragma unroll
        for (int i = 0; i < 4; ++i)
            gload16(Ap + (size_t)(m0 + i * 32 + rA) * ldA + kt + cSw * 8,
                    (char*)As + i * 4096 + wid * 1024);
#pragma unroll
        for (int i = 0; i < 4; ++i)
            gload16(Btp + (size_t)(n0 + i * 32 + rA) * ldB + kt + cSw * 8,
                    (char*)Bs + i * 4096 + wid * 1024);
        __syncthreads();
#pragma unroll
        for (int ks = 0; ks < 2; ++ks) {
            const int kb = (ks * 64 + ((lane >> 4) << 4)) ^ xorMask;
            v8bf af[4], bfr[4];
#pragma unroll
            for (int f = 0; f < 4; ++f) {
                af[f]  = *(const v8bf*)((const char*)As + (wm * 64 + f * 16 + l15) * 128 + kb);
                bfr[f] = *(const v8bf*)((const char*)Bs + (wn * 64 + f * 16 + l15) * 128 + kb);
            }
#pragma unroll
            for (int i = 0; i < 4; ++i)
#pragma unroll
                for (int j = 0; j < 4; ++j)
                    acc[i][j] = __builtin_amdgcn_mfma_f32_16x16x32_bf16(af[i], bfr[j], acc[i][j], 0, 0, 0);
        }
        __syncthreads();
    }
    const int cc = lane & 15, r4 = (lane >> 4) << 2;
#pragma unroll
    for (int i = 0; i < 4; ++i)
#pragma unroll
        for (int j = 0; j < 4; ++j)
#pragma unroll
            for (int r = 0; r < 4; ++r) {
                const int gm = m0 + wm * 64 + i * 16 + r4 + r;
                const int gn = n0 + wn * 64 + j * 16 + cc;
                Ob[(size_t)gm * ldO + gn] = (__bf16)acc[i][j][r];
            }
}

// ---- penta: z0 G_AD=A@D^T, z1 G_BC=B@C^T (K=D), z2 Pm, z3 Qm (K=2D),
//      z4: aux slice — pbeta rows + node terms ----
__global__ __launch_bounds__(256, 5) void gemm64_penta(
    const __bf16* __restrict__ ACBD, const __bf16* __restrict__ KoKs,
    float* __restrict__ G_AD, float* __restrict__ G_BC,
    float* __restrict__ Pm, float* __restrict__ Qm,
    const float* __restrict__ bs, const float* __restrict__ bo,
    float* __restrict__ pb, float* __restrict__ nodeS, float* __restrict__ nodeO,
    int Nn, int Dd) {
    const int z = blockIdx.z;
    if (z == 4) {
        const int bb = blockIdx.y * 16 + blockIdx.x;
        const int w = threadIdx.x >> 6, lane = threadIdx.x & 63;
        {
            const int d = bb * 4 + w;
            float a = 0.f;
            for (int j = lane; j < Dd; j += 64)
                a += bs[j] * (float)KoKs[(size_t)d * 2048 + j] +
                     bo[j] * (float)KoKs[(size_t)d * 2048 + 1024 + j];
            a = wave_reduce_sum(a);
            if (lane == 0) pb[d] = a;
        }
        if (bb * 4 + w < Nn) {
            const int n = bb * 4 + w;
            const int d0 = lane * 16;
            const __bf16* row = ACBD + (size_t)n * 4 * Dd;
            const __bf16* pa = row + d0;
            const __bf16* pc = row + Dd + d0;
            const __bf16* pB = row + 2 * Dd + d0;
            const __bf16* pd = row + 3 * Dd + d0;
            float s1 = 0.f, s2 = 0.f;
#pragma unroll
            for (int u = 0; u < 16; ++u) {
                float a = (float)pa[u], c = (float)pc[u], b = (float)pB[u], dd = (float)pd[u];
                float vs_ = bs[d0 + u], vo_ = bo[d0 + u];
                s1 += a * c + a * vo_ + vs_ * c;
                s2 += b * dd + b * vo_ + vs_ * dd;
            }
            s1 = wave_reduce_sum(s1);
            s2 = wave_reduce_sum(s2);
            if (lane == 0) { nodeS[n] = s1; nodeO[n] = s2; }
        }
        return;
    }

    const __bf16* Ap = ACBD + (size_t)(z & 1) * 2 * Dd;
    const int ldA = 4 * Dd;
    const __bf16* Btp; int ldB, Nv, K; float* Of; int ldO;
    if (z == 0)      { Btp = ACBD + 3 * Dd; ldB = 4 * Dd; Nv = Nn; K = Dd;     Of = G_AD; ldO = Nn; }
    else if (z == 1) { Btp = ACBD + 1 * Dd; ldB = 4 * Dd; Nv = Nn; K = Dd;     Of = G_BC; ldO = Nn; }
    else             { Btp = KoKs;          ldB = 2 * Dd; Nv = Dd; K = 2 * Dd; Of = (z == 2) ? Pm : Qm; ldO = Dd; }
    const int m0 = blockIdx.x * 64, n0 = blockIdx.y * 64;
    if (m0 >= Nn || n0 >= Nv) return;

    __shared__ alignas(16) __bf16 As[64 * 64];
    __shared__ alignas(16) __bf16 Bs[64 * 64];
    const int t = threadIdx.x, lane = t & 63, wid = t >> 6;
    const int wm = wid >> 1, wn = wid & 1;
    const int rA = t >> 3;
    const int cSw = (t & 7) ^ (rA & 7);
    const int l15 = lane & 15;
    const int xorMask = (l15 & 7) << 4;
    v4f acc[2][2] = {};

    for (int kt = 0; kt < K; kt += 64) {
#pragma unroll
        for (int i = 0; i < 2; ++i)
            gload16(Ap + (size_t)(m0 + i * 32 + rA) * ldA + kt + cSw * 8,
                    (char*)As + i * 4096 + wid * 1024);
#pragma unroll
        for (int i = 0; i < 2; ++i)
            gload16(Btp + (size_t)(n0 + i * 32 + rA) * ldB + kt + cSw * 8,
                    (char*)Bs + i * 4096 + wid * 1024);
        __syncthreads();
#pragma unroll
        for (int ks = 0; ks < 2; ++ks) {
            const int kb = (ks * 64 + ((lane >> 4) << 4)) ^ xorMask;
            v8bf af[2], bfr[2];
#pragma unroll
            for (int f = 0; f < 2; ++f) {
                af[f]  = *(const v8bf*)((const char*)As + (wm * 32 + f * 16 + l15) * 128 + kb);
                bfr[f] = *(const v8bf*)((const char*)Bs + (wn * 32 + f * 16 + l15) * 128 + kb);
            }
#pragma unroll
            for (int i = 0; i < 2; ++i)
#pragma unroll
                for (int j = 0; j < 2; ++j)
                    acc[i][j] = __builtin_amdgcn_mfma_f32_16x16x32_bf16(af[i], bfr[j], acc[i][j], 0, 0, 0);
        }
        __syncthreads();
    }
    const int cc = lane & 15, r4 = (lane >> 4) << 2;
#pragma unroll
    for (int i = 0; i < 2; ++i)
#pragma unroll
        for (int j = 0; j < 2; ++j)
#pragma unroll
            for (int r = 0; r < 4; ++r) {
                const int gm = m0 + wm * 32 + i * 16 + r4 + r;
                const int gn = n0 + wn * 32 + j * 16 + cc;
                Of[(size_t)gm * ldO + gn] = acc[i][j][r];
            }
}

// ---------------- small custom kernels ----------------

__global__ __launch_bounds__(256) void edge_lmax_kernel(
    const float* __restrict__ q,
    const float* __restrict__ nodeS, const float* __restrict__ nodeO,
    const float* __restrict__ G_AD, const float* __restrict__ G_BC,
    const int* __restrict__ sbj, const int* __restrict__ obj,
    float* __restrict__ logits, unsigned* __restrict__ mS, unsigned* __restrict__ mO,
    int E, int Nn, float scale) {
    int e = blockIdx.x * 256 + threadIdx.x;
    if (e >= E) return;
    int s = sbj[e], o = obj[e];
    float l = (q[e] + nodeS[s] + nodeO[o] +
               G_AD[(size_t)s * Nn + o] + G_BC[(size_t)o * Nn + s]) * scale;
    logits[e] = l;
    unsigned k = fenc(l);
    atomicMax(mS + s, k);
    atomicMax(mO + o, k);
}

__global__ __launch_bounds__(256) void expsum_kernel(const float* __restrict__ logits,
                                                     const int* __restrict__ sbj,
                                                     const int* __restrict__ obj,
                                                     const unsigned* __restrict__ mS,
                                                     const unsigned* __restrict__ mO,
                                                     float* __restrict__ es, float* __restrict__ eo,
                                                     float* __restrict__ sumS, float* __restrict__ sumO,
                                                     int E) {
    int e = blockIdx.x * 256 + threadIdx.x;
    if (e >= E) return;
    float l = logits[e];
    int s = sbj[e], o = obj[e];
    float a = expf(l - fdec(mS[s]));
    es[e] = a;
    atomicAdd(sumS + s, a);
    float b = expf(l - fdec(mO[o]));
    eo[e] = b;
    atomicAdd(sumO + o, b);
}

__global__ __launch_bounds__(256) void scatter_kernel(const float* __restrict__ es,
                                                      const float* __restrict__ eo,
                                                      const float* __restrict__ sumS,
                                                      const float* __restrict__ sumO,
                                                      const int* __restrict__ sbj,
                                                      const int* __restrict__ obj,
                                                      float* __restrict__ S, int* __restrict__ inv,
                                                      int E, int Nn) {
    int e = blockIdx.x * 256 + threadIdx.x;
    if (e >= E) return;
    int s = sbj[e], o = obj[e];
    atomicAdd(S + (size_t)s * Nn + o, es[e] / sumS[s]);
    atomicAdd(S + (size_t)o * Nn + s, eo[e] / sumO[o]);
    inv[s] = 1;
    inv[o] = 1;
}

// ---------------- host launcher ----------------

extern "C" void kernel_launch(void* const* d_in, const int* in_sizes, int n_in,
                              void* d_out, int out_size, void* d_ws, size_t ws_size,
                              hipStream_t stream) {
    const float* V     = (const float*)d_in[0];
    const float* relv  = (const float*)d_in[1];
    const float* W_rel = (const float*)d_in[2];
    const float* b_rel = (const float*)d_in[3];
    const float* W_sbj = (const float*)d_in[4];
    const float* b_sbj = (const float*)d_in[5];
    const float* W_obj = (const float*)d_in[6];
    const float* b_obj = (const float*)d_in[7];
    const float* W_ctx = (const float*)d_in[8];
    const float* b_ctx = (const float*)d_in[9];
    const int* sbj = (const int*)d_in[10];
    const int* obj = (const int*)d_in[11];

    const int D  = in_sizes[3];
    const int E  = in_sizes[10];
    const int Nn = in_sizes[12];
    const size_t DD = (size_t)D * D;

    const float* Ws_r = W_sbj + DD;
    const float* Wo_r = W_obj + DD;

    char* ws = (char*)d_ws;
    size_t off = 0;
    auto alloc = [&](size_t bytes) -> void* {
        void* p = (void*)(ws + off);
        off += (bytes + 255) & ~(size_t)255;
        return p;
    };

    // persistent
    __bf16* relv_b = (__bf16*)alloc((size_t)E * D * 2);
    __bf16* Vb     = (__bf16*)alloc((size_t)Nn * D * 2);
    __bf16* VbT    = (__bf16*)alloc((size_t)D * Nn * 2);
    __bf16* ZT_b   = (__bf16*)alloc(DD * 2);
    __bf16* KoKs   = (__bf16*)alloc((size_t)D * 2 * D * 2);   // [D][2048] = [Ko | Ks]
    __bf16* ACBD   = (__bf16*)alloc((size_t)Nn * 4 * D * 2);  // [Nn][4D] = [A|C|B|D]
    __bf16* Ws_vT  = (__bf16*)alloc(DD * 2);
    __bf16* Wo_vT  = (__bf16*)alloc(DD * 2);
    __bf16* W_ctxT = (__bf16*)alloc(DD * 2);
    // region R1: Wr_all (3DD bf16) ... later G_AD+G_BC (2*Nn*Nn f32)
    size_t r1 = off;
    __bf16* Wr_all = (__bf16*)(ws + r1);
    float*  G_AD   = (float*)(ws + r1);
    float*  G_BC   = G_AD + (size_t)Nn * Nn;
    {
        size_t a = 3 * DD * 2, b = 2 * (size_t)Nn * Nn * 4;
        off += ((a > b ? a : b) + 255) & ~(size_t)255;
    }
    __bf16* WoWs_T = (__bf16*)alloc(2 * DD * 2);
    // region R3: MT_all (4DD bf16) ... later Pm+Qm
    size_t r3 = off;
    __bf16* MT_all = (__bf16*)(ws + r3);
    float*  Pm     = (float*)(ws + r3);
    float*  Qm     = Pm + (size_t)Nn * D;
    {
        size_t a = 4 * DD * 2, b = 2 * (size_t)Nn * D * 4;
        off += ((a > b ? a : b) + 255) & ~(size_t)255;
    }
    float* pb     = (float*)alloc((size_t)D * 4);
    float* nodeS  = (float*)alloc((size_t)Nn * 4);
    float* nodeO  = (float*)alloc((size_t)Nn * 4);
    float* logits = (float*)alloc((size_t)E * 4);
    float* es     = (float*)alloc((size_t)E * 4);
    float* eo     = (float*)alloc((size_t)E * 4);
    size_t zbeg = off;
    float* S      = (float*)alloc((size_t)Nn * Nn * 4);
    float* q      = (float*)alloc((size_t)E * 4);
    float* bs     = (float*)alloc((size_t)D * 4);
    float* bo     = (float*)alloc((size_t)D * 4);
    unsigned* mS  = (unsigned*)alloc((size_t)Nn * 4);
    unsigned* mO  = (unsigned*)alloc((size_t)Nn * 4);
    float* sumS   = (float*)alloc((size_t)Nn * 4);
    float* sumO   = (float*)alloc((size_t)Nn * 4);
    int* inv      = (int*)alloc((size_t)Nn * 4);
    size_t zend = off;
    __bf16* Sb    = (__bf16*)alloc((size_t)Nn * Nn * 2);
    __bf16* ctx_b = (__bf16*)alloc((size_t)Nn * D * 2);
    (void)ws_size; (void)n_in; (void)out_size;

    float* outVj = (float*)d_out + (size_t)E * D;

    // 1. zero atomic buffers (incl. bs/bo for megacvt's beta fold)
    hipMemsetAsync(ws + zbeg, 0, zend - zbeg, stream);

    // 2. megacvt: beta + six transposes FIRST (hide under the stream), then
    //    relv copy+cvt / W_rel cvt / V cvt at 32 B/thread with NT stores
    {
        long long nr = (long long)E * D, nw = 3 * (long long)DD, nv = (long long)Nn * D;
        long long NBs = (nr + nw + nv) / 8 / 256;
        long long total = 256 + 6LL * (D / 32) * (D / 32) + NBs;
        megacvt<<<dim3((unsigned)total), dim3(256), 0, stream>>>(
            relv, (float*)d_out, relv_b, nr, W_rel, Wr_all, nw, V, Vb, nv,
            b_rel, b_sbj, b_obj, Ws_r, Wo_r, bs, bo, D, Nn,
            WoWs_T, Ws_vT, Wo_vT, VbT, W_ctx, W_ctxT);
    }

    // 3. merged W-side precompute (384 blocks): MT_all quadrants + KoKs
    gemm_gl<5, true><<<dim3(24, 16), dim3(256), 0, stream>>>(
        WoWs_T, D, Wr_all, D, 3 * D, 2 * D, D, nullptr, 0, nullptr, MT_all, D,
        KoKs, Ws_vT, nullptr, nullptr, nullptr, nullptr, nullptr, Wo_vT);

    // 4. ZT = Ko@Ks^T  ||  ACBD = Vb@MT_all^T, one 128²-tile dispatch (z=2)
    gemm128_pair<<<dim3(8, 32, 2), dim3(256), 0, stream>>>(
        KoKs + 0, 2 * D, KoKs + D, 2 * D, D, D, ZT_b, D,
        Vb, D, MT_all, D, Nn, 4 * D, ACBD, 4 * D, D);

    // 5. penta: Grams + P/Q + (pbeta, node) in one dispatch (z=5)
    gemm64_penta<<<dim3(16, 16, 5), dim3(256), 0, stream>>>(
        ACBD, KoKs, G_AD, G_BC, Pm, Qm, bs, bo, pb, nodeS, nodeO, Nn, D);

    // 6. heavy: q[e] = (relv@Z).relv + relv.(Pm[s]+Qm[o]+pb)
    //    flat grid + chunked XCD swizzle for A-panel L2 reuse
    gemm_gl<3, true><<<dim3((E / 128) * (D / 128)), dim3(256), 0, stream>>>(
        relv_b, D, ZT_b, D, E, D, D, Pm, D, Qm, nullptr, 0, nullptr,
        relv_b, q, pb, nullptr, sbj, obj, nullptr);

    // 7-9. scalar logits + segment max, expsum, scatter
    edge_lmax_kernel<<<dim3(E / 256), dim3(256), 0, stream>>>(
        q, nodeS, nodeO, G_AD, G_BC, sbj, obj, logits, mS, mO, E, Nn, 1.0f / sqrtf((float)D));
    expsum_kernel<<<dim3(E / 256), dim3(256), 0, stream>>>(logits, sbj, obj, mS, mO, es, eo, sumS, sumO, E);
    scatter_kernel<<<dim3(E / 256), dim3(256), 0, stream>>>(es, eo, sumS, sumO, sbj, obj, S, inv, E, Nn);

    // 10. S -> bf16
    {
        size_t n = (size_t)Nn * Nn;
        cvt_f32_bf16<<<dim3((int)((n / 4 + 255) / 256)), dim3(256), 0, stream>>>(S, Sb, (long long)n);
    }
    // 11. ctx = S @ V
    gemm_gl<0, false><<<dim3(Nn / 64, D / 64), dim3(256), 0, stream>>>(
        Sb, Nn, VbT, Nn, Nn, D, Nn, nullptr, 0, nullptr, ctx_b, D,
        nullptr, nullptr, nullptr, nullptr, nullptr, nullptr, nullptr, nullptr);
    // 12. vj = V + mask * (ctx @ W_ctx + b_ctx)
    gemm_gl<4, false><<<dim3(Nn / 64, D / 64), dim3(256), 0, stream>>>(
        ctx_b, D, W_ctxT, D, Nn, D, D, V, D, outVj, nullptr, D,
        nullptr, nullptr, nullptr, b_ctx, inv, nullptr, nullptr, nullptr);
}

// Round 13
// 321.002 us; speedup vs baseline: 1.4167x; 1.4167x over previous
//
#include <hip/hip_runtime.h>
#include <hip/hip_bf16.h>
#include <math.h>
#include <type_traits>

typedef __bf16 v8bf __attribute__((ext_vector_type(8)));
typedef __bf16 v4bf __attribute__((ext_vector_type(4)));
typedef float  v4f  __attribute__((ext_vector_type(4)));

__device__ __forceinline__ float wave_reduce_sum(float v) {
#pragma unroll
    for (int m = 1; m < 64; m <<= 1) v += __shfl_xor(v, m, 64);
    return v;
}

__device__ __forceinline__ unsigned fenc(float x) {
    unsigned u = __float_as_uint(x);
    return (u & 0x80000000u) ? ~u : (u | 0x80000000u);
}
__device__ __forceinline__ float fdec(unsigned k) {
    return (k & 0x80000000u) ? __uint_as_float(k ^ 0x80000000u) : __uint_as_float(~k);
}

__device__ __forceinline__ void gload16(const void* g, void* l) {
    __builtin_amdgcn_global_load_lds((const __attribute__((address_space(1))) void*)g,
                                     (__attribute__((address_space(3))) void*)l, 16, 0, 0);
}

// ---------------- conversion kernels ----------------

__global__ __launch_bounds__(256) void cvt_f32_bf16(const float* __restrict__ in,
                                                    __bf16* __restrict__ out, long long n) {
    long long i = ((long long)blockIdx.x * 256 + threadIdx.x) * 4;
    if (i >= n) return;
    v4f v = *(const v4f*)(in + i);
    v4bf o;
    o[0] = (__bf16)v[0]; o[1] = (__bf16)v[1]; o[2] = (__bf16)v[2]; o[3] = (__bf16)v[3];
    *(v4bf*)(out + i) = o;
}

// Router grid (small latency-bound work FIRST so it hides under the stream):
//   blocks [0,256): beta (bs = b_sbj + b_rel@Ws_r ; bo = b_obj + b_rel@Wo_r)
//   blocks [256, 256+6*perz): six transpose-convert slices (32x32 tiles)
//   blocks [256+6*perz, ...): relv copy+cvt | W_rel cvt | V cvt, 8 floats/thread,
//                             non-temporal stores for write-once data
__global__ __launch_bounds__(256) void megacvt(
    const float* __restrict__ relv, float* __restrict__ outCopy, __bf16* __restrict__ relv_b,
    long long nr,
    const float* __restrict__ wrel, __bf16* __restrict__ wrel_b, long long nw,
    const float* __restrict__ vsrc, __bf16* __restrict__ v_b, long long nv,
    const float* __restrict__ b_rel, const float* __restrict__ b_sbj, const float* __restrict__ b_obj,
    const float* __restrict__ Wsr, const float* __restrict__ Wor,
    float* __restrict__ bs, float* __restrict__ bo, int D, int Nn,
    __bf16* __restrict__ WoWs_T, __bf16* __restrict__ Ws_vT, __bf16* __restrict__ Wo_vT,
    __bf16* __restrict__ VbT, const float* __restrict__ W_ctx, __bf16* __restrict__ W_ctxT) {
    __shared__ float tile[32][33];
    const int perz = (D / 32) * (D / 32);
    const long long blk = blockIdx.x;
    const size_t DDl = (size_t)D * D;

    if (blk < 256) {
        // beta: 2-stage bias projection, coalesced row-major reads, atomicAdd partials
        int bb = (int)blk;
        const int col = (bb & 3) * 256 + threadIdx.x;
        const int chunk = (bb >> 2) & 31;
        const int mat = bb >> 7;
        const int rpc = D / 32;
        const int r0 = chunk * rpc;
        const float* W = (mat == 0) ? Wsr : Wor;
        float acc = 0.f;
        if (chunk == 0) acc = (mat == 0) ? b_sbj[col] : b_obj[col];
        for (int r = r0; r < r0 + rpc; ++r)
            acc += b_rel[r] * W[(size_t)r * D + col];
        atomicAdd(((mat == 0) ? bs : bo) + col, acc);
        return;
    }
    if (blk < 256 + 6LL * perz) {
        int tb = (int)(blk - 256);
        int z = tb / perz, rem = tb % perz;
        const float* ins[6];
        __bf16* outs[6];
        int Rs[6];
        ins[0] = Wor;        outs[0] = WoWs_T;       Rs[0] = D;   // Wo_r^T
        ins[1] = Wsr;        outs[1] = WoWs_T + DDl; Rs[1] = D;   // Ws_r^T
        ins[2] = Wsr - DDl;  outs[2] = Ws_vT;        Rs[2] = D;   // Ws_v^T (= W_sbj[:D])
        ins[3] = Wor - DDl;  outs[3] = Wo_vT;        Rs[3] = D;   // Wo_v^T (= W_obj[:D])
        ins[4] = vsrc;       outs[4] = VbT;          Rs[4] = Nn;  // V^T
        ins[5] = W_ctx;      outs[5] = W_ctxT;       Rs[5] = D;   // W_ctx^T
        const float* in = ins[z];
        __bf16* out = outs[z];
        const int R = Rs[z], C = D;
        int cb = (rem % (D / 32)) * 32, rb = (rem / (D / 32)) * 32;
        if (cb >= C || rb >= R) return;
        int tx = threadIdx.x & 31, ty = threadIdx.x >> 5;
#pragma unroll
        for (int i = 0; i < 32; i += 8)
            tile[ty + i][tx] = in[(size_t)(rb + ty + i) * C + cb + tx];
        __syncthreads();
#pragma unroll
        for (int i = 0; i < 32; i += 8)
            out[(size_t)(cb + ty + i) * R + rb + tx] = (__bf16)tile[tx][ty + i];
        return;
    }
    // stream: 8 floats per thread
    long long i = ((blk - 256 - 6LL * perz) * 256 + threadIdx.x) * 8;
    if (i < nr) {
        v4f a = *(const v4f*)(relv + i);
        v4f b = *(const v4f*)(relv + i + 4);
        __builtin_nontemporal_store(a, (v4f*)(outCopy + i));
        __builtin_nontemporal_store(b, (v4f*)(outCopy + i + 4));
        v8bf o;
        o[0] = (__bf16)a[0]; o[1] = (__bf16)a[1]; o[2] = (__bf16)a[2]; o[3] = (__bf16)a[3];
        o[4] = (__bf16)b[0]; o[5] = (__bf16)b[1]; o[6] = (__bf16)b[2]; o[7] = (__bf16)b[3];
        __builtin_nontemporal_store(o, (v8bf*)(relv_b + i));
    } else if (i < nr + nw) {
        long long j = i - nr;
        v4f a = *(const v4f*)(wrel + j);
        v4f b = *(const v4f*)(wrel + j + 4);
        v8bf o;
        o[0] = (__bf16)a[0]; o[1] = (__bf16)a[1]; o[2] = (__bf16)a[2]; o[3] = (__bf16)a[3];
        o[4] = (__bf16)b[0]; o[5] = (__bf16)b[1]; o[6] = (__bf16)b[2]; o[7] = (__bf16)b[3];
        *(v8bf*)(wrel_b + j) = o;
    } else if (i < nr + nw + nv) {
        long long j = i - nr - nw;
        v4f a = *(const v4f*)(vsrc + j);
        v4f b = *(const v4f*)(vsrc + j + 4);
        v8bf o;
        o[0] = (__bf16)a[0]; o[1] = (__bf16)a[1]; o[2] = (__bf16)a[2]; o[3] = (__bf16)a[3];
        o[4] = (__bf16)b[0]; o[5] = (__bf16)b[1]; o[6] = (__bf16)b[2]; o[7] = (__bf16)b[3];
        *(v8bf*)(v_b + j) = o;
    }
}

// ---- bf16 MFMA GEMM, m97 structure + XOR-swizzled LDS ----
// __launch_bounds__(256, 4): VGPR 64, no spill (R12's (256,5) clamped VGPR to 48 ->
// 160 MB scratch spill traffic, heavy 81->160 us. Do not raise past 4.)
// MODE 0: outB (bf16, plain, ldOut) = acc (+addMat f32 [ldAdd] if non-null)
// MODE 3: fused logits partial (flat grid + chunked XCD swizzle)
// MODE 4: outF[m][n] = addMat[m][n] + (maskRow[m] ? acc + addRow[n] : 0)
// MODE 5: merged W-side: m-blocks 0-1 -> MT quadrants; m-block 2 -> KoKs.
template <int MODE, bool BIG>
__global__ __launch_bounds__(256, 4) void gemm_gl(
    const __bf16* __restrict__ Ap, int ldA,
    const __bf16* __restrict__ Btp, int ldB,
    int M, int N, int K,
    const float* __restrict__ addMat, int ldAdd,
    float* __restrict__ outF,
    __bf16* __restrict__ outB, int ldOut,
    __bf16* __restrict__ outB2,
    const __bf16* __restrict__ rbDot,
    float* __restrict__ qOut,
    const float* __restrict__ addRow,
    const int* __restrict__ maskRow,
    const int* __restrict__ sbjI,
    const int* __restrict__ objI,
    const __bf16* __restrict__ auxW) {
    constexpr int BM = BIG ? 128 : 64;
    constexpr int BN = BIG ? 128 : 64;
    constexpr int WM = BM / 2, WN = BN / 2;
    constexpr int FI = WM / 16, FJ = WN / 16;
    constexpr int NLA = (BM * 64) / 2048;
    constexpr int NLB = (BN * 64) / 2048;

    __shared__ alignas(16) __bf16 As[BM * 64];
    __shared__ alignas(16) __bf16 Bs[BN * 64];

    int m0, n0;
    if constexpr (MODE == 3) {
        // flat grid, chunked XCD swizzle: id%8 = mb%8 (panel pinned to one XCD);
        // the panel's 8 n-blocks are 8 ids apart -> temporally adjacent -> L2 reuse.
        const int id = blockIdx.x;
        const int mb = (id >> 6) * 8 + (id & 7);
        const int nb = (id >> 3) & 7;
        m0 = mb * BM;
        n0 = nb * BN;
    } else {
        m0 = blockIdx.x * BM;
        n0 = blockIdx.y * BN;
    }
    bool kRows = false;
    if constexpr (MODE == 5) {
        if (m0 >= 2048) {  // KoKs rows: A = Wr_r (= Btp + 2*K*K), Bt = WoWs_T (= Ap)
            kRows = true;
            const __bf16* t = Ap;
            Ap = Btp + (size_t)2 * K * K;
            Btp = t;
            m0 -= 2048;
        }
    }

    const int t = threadIdx.x, lane = t & 63, wid = t >> 6;
    const int wm = wid >> 1, wn = wid & 1;
    const int rA = t >> 3;
    const int cSw = (t & 7) ^ (rA & 7);            // swizzled 16B-chunk (involution)

    v4f acc[FI][FJ] = {};

    const int l15 = lane & 15;
    const int xorMask = (l15 & 7) << 4;            // read-side XOR (bytes)

    for (int kt = 0; kt < K; kt += 64) {
#pragma unroll
        for (int i = 0; i < NLA; ++i)
            gload16(Ap + (size_t)(m0 + i * 32 + rA) * ldA + kt + cSw * 8,
                    (char*)As + i * 4096 + wid * 1024);
#pragma unroll
        for (int i = 0; i < NLB; ++i)
            gload16(Btp + (size_t)(n0 + i * 32 + rA) * ldB + kt + cSw * 8,
                    (char*)Bs + i * 4096 + wid * 1024);
        __syncthreads();
#pragma unroll
        for (int ks = 0; ks < 2; ++ks) {
            const int kb = (ks * 64 + ((lane >> 4) << 4)) ^ xorMask;
            v8bf af[FI], bfr[FJ];
#pragma unroll
            for (int f = 0; f < FI; ++f)
                af[f] = *(const v8bf*)((const char*)As + (wm * WM + f * 16 + l15) * 128 + kb);
#pragma unroll
            for (int f = 0; f < FJ; ++f)
                bfr[f] = *(const v8bf*)((const char*)Bs + (wn * WN + f * 16 + l15) * 128 + kb);
#pragma unroll
            for (int i = 0; i < FI; ++i)
#pragma unroll
                for (int j = 0; j < FJ; ++j)
                    acc[i][j] = __builtin_amdgcn_mfma_f32_16x16x32_bf16(af[i], bfr[j], acc[i][j], 0, 0, 0);
        }
        __syncthreads();
    }

    const int cc = lane & 15, r4 = (lane >> 4) << 2;
    if constexpr (MODE == 3) {
#pragma unroll
        for (int i = 0; i < FI; ++i)
#pragma unroll
            for (int r = 0; r < 4; ++r) {
                const int gm = m0 + wm * WM + i * 16 + r4 + r;
                const int s = sbjI[gm], o = objI[gm];
                const float* Ps = addMat + (size_t)s * ldAdd;
                const float* Qo = outF + (size_t)o * ldAdd;
                float p = 0.f;
#pragma unroll
                for (int j = 0; j < FJ; ++j) {
                    const int gn = n0 + wn * WN + j * 16 + cc;
                    float rv = (float)rbDot[(size_t)gm * N + gn];
                    p += rv * (acc[i][j][r] + Ps[gn] + Qo[gn] + addRow[gn]);
                }
                p += __shfl_xor(p, 1, 64);
                p += __shfl_xor(p, 2, 64);
                p += __shfl_xor(p, 4, 64);
                p += __shfl_xor(p, 8, 64);
                if (cc == 0) atomicAdd(qOut + gm, p);
            }
    } else if constexpr (MODE == 5) {
        if (kRows) {
#pragma unroll
            for (int i = 0; i < FI; ++i)
#pragma unroll
                for (int j = 0; j < FJ; ++j)
#pragma unroll
                    for (int r = 0; r < 4; ++r) {
                        const int gm = m0 + wm * WM + i * 16 + r4 + r;
                        const int gn = n0 + wn * WN + j * 16 + cc;
                        outB2[(size_t)gm * 2048 + gn] = (__bf16)acc[i][j][r];
                    }
        } else {
            const int mb = m0 >> 10, nb = n0 >> 10;
            const int blk = (mb == 0) ? (nb ? 3 : 1) : (nb ? 2 : 0);
            const __bf16* addB = (blk == 0) ? rbDot : (blk == 3 ? auxW : nullptr);
            const size_t DDe = (size_t)ldOut * ldOut;
            __bf16* dst = outB + (size_t)blk * DDe;
#pragma unroll
            for (int i = 0; i < FI; ++i)
#pragma unroll
                for (int j = 0; j < FJ; ++j)
#pragma unroll
                    for (int r = 0; r < 4; ++r) {
                        const int gml = (m0 + wm * WM + i * 16 + r4 + r) & 1023;
                        const int gnl = (n0 + wn * WN + j * 16 + cc) & 1023;
                        float v = acc[i][j][r];
                        if (addB) v += (float)addB[(size_t)gml * ldOut + gnl];
                        dst[(size_t)gml * ldOut + gnl] = (__bf16)v;
                    }
        }
    } else {
#pragma unroll
        for (int i = 0; i < FI; ++i)
#pragma unroll
            for (int j = 0; j < FJ; ++j)
#pragma unroll
                for (int r = 0; r < 4; ++r) {
                    const int gm = m0 + wm * WM + i * 16 + r4 + r;
                    const int gn = n0 + wn * WN + j * 16 + cc;
                    float v = acc[i][j][r];
                    if constexpr (MODE == 0) {
                        if (addMat) v += addMat[(size_t)gm * ldAdd + gn];
                        outB[(size_t)gm * ldOut + gn] = (__bf16)v;
                    } else {  // MODE 4
                        float u = addMat[(size_t)gm * ldAdd + gn];
                        if (maskRow[gm]) u += v + addRow[gn];
                        outF[(size_t)gm * ldOut + gn] = u;
                    }
                }
    }
}

// ---- batched pair at 128² tiles: z=0 ZT = Ko@Ks^T ; z=1 ACBD = Vb@MT_all^T ----
__global__ __launch_bounds__(256, 4) void gemm128_pair(
    const __bf16* __restrict__ A0, int ldA0, const __bf16* __restrict__ B0, int ldB0,
    int M0v, int N0v, __bf16* __restrict__ O0, int ldO0,
    const __bf16* __restrict__ A1, int ldA1, const __bf16* __restrict__ B1, int ldB1,
    int M1v, int N1v, __bf16* __restrict__ O1, int ldO1, int K) {
    const __bf16* Ap; const __bf16* Btp; __bf16* Ob;
    int ldA, ldB, Mv, Nv, ldO;
    if (blockIdx.z == 0) { Ap = A0; Btp = B0; Ob = O0; ldA = ldA0; ldB = ldB0; Mv = M0v; Nv = N0v; ldO = ldO0; }
    else                 { Ap = A1; Btp = B1; Ob = O1; ldA = ldA1; ldB = ldB1; Mv = M1v; Nv = N1v; ldO = ldO1; }
    const int m0 = blockIdx.x * 128, n0 = blockIdx.y * 128;
    if (m0 >= Mv || n0 >= Nv) return;

    __shared__ alignas(16) __bf16 As[128 * 64];
    __shared__ alignas(16) __bf16 Bs[128 * 64];
    const int t = threadIdx.x, lane = t & 63, wid = t >> 6;
    const int wm = wid >> 1, wn = wid & 1;
    const int rA = t >> 3;
    const int cSw = (t & 7) ^ (rA & 7);
    const int l15 = lane & 15;
    const int xorMask = (l15 & 7) << 4;
    v4f acc[4][4] = {};

    for (int kt = 0; kt < K; kt += 64) {
#pragma unroll
        for (int i = 0; i < 4; ++i)
            gload16(Ap + (size_t)(m0 + i * 32 + rA) * ldA + kt + cSw * 8,
                    (char*)As + i * 4096 + wid * 1024);
#pragma unroll
        for (int i = 0; i < 4; ++i)
            gload16(Btp + (size_t)(n0 + i * 32 + rA) * ldB + kt + cSw * 8,
                    (char*)Bs + i * 4096 + wid * 1024);
        __syncthreads();
#pragma unroll
        for (int ks = 0; ks < 2; ++ks) {
            const int kb = (ks * 64 + ((lane >> 4) << 4)) ^ xorMask;
            v8bf af[4], bfr[4];
#pragma unroll
            for (int f = 0; f < 4; ++f) {
                af[f]  = *(const v8bf*)((const char*)As + (wm * 64 + f * 16 + l15) * 128 + kb);
                bfr[f] = *(const v8bf*)((const char*)Bs + (wn * 64 + f * 16 + l15) * 128 + kb);
            }
#pragma unroll
            for (int i = 0; i < 4; ++i)
#pragma unroll
                for (int j = 0; j < 4; ++j)
                    acc[i][j] = __builtin_amdgcn_mfma_f32_16x16x32_bf16(af[i], bfr[j], acc[i][j], 0, 0, 0);
        }
        __syncthreads();
    }
    const int cc = lane & 15, r4 = (lane >> 4) << 2;
#pragma unroll
    for (int i = 0; i < 4; ++i)
#pragma unroll
        for (int j = 0; j < 4; ++j)
#pragma unroll
            for (int r = 0; r < 4; ++r) {
                const int gm = m0 + wm * 64 + i * 16 + r4 + r;
                const int gn = n0 + wn * 64 + j * 16 + cc;
                Ob[(size_t)gm * ldO + gn] = (__bf16)acc[i][j][r];
            }
}

// ---- penta: z0 G_AD=A@D^T, z1 G_BC=B@C^T (K=D), z2 Pm, z3 Qm (K=2D),
//      z4: aux slice — pbeta rows + node terms ----
__global__ __launch_bounds__(256, 4) void gemm64_penta(
    const __bf16* __restrict__ ACBD, const __bf16* __restrict__ KoKs,
    float* __restrict__ G_AD, float* __restrict__ G_BC,
    float* __restrict__ Pm, float* __restrict__ Qm,
    const float* __restrict__ bs, const float* __restrict__ bo,
    float* __restrict__ pb, float* __restrict__ nodeS, float* __restrict__ nodeO,
    int Nn, int Dd) {
    const int z = blockIdx.z;
    if (z == 4) {
        const int bb = blockIdx.y * 16 + blockIdx.x;
        const int w = threadIdx.x >> 6, lane = threadIdx.x & 63;
        {
            const int d = bb * 4 + w;
            float a = 0.f;
            for (int j = lane; j < Dd; j += 64)
                a += bs[j] * (float)KoKs[(size_t)d * 2048 + j] +
                     bo[j] * (float)KoKs[(size_t)d * 2048 + 1024 + j];
            a = wave_reduce_sum(a);
            if (lane == 0) pb[d] = a;
        }
        if (bb * 4 + w < Nn) {
            const int n = bb * 4 + w;
            const int d0 = lane * 16;
            const __bf16* row = ACBD + (size_t)n * 4 * Dd;
            const __bf16* pa = row + d0;
            const __bf16* pc = row + Dd + d0;
            const __bf16* pB = row + 2 * Dd + d0;
            const __bf16* pd = row + 3 * Dd + d0;
            float s1 = 0.f, s2 = 0.f;
#pragma unroll
            for (int u = 0; u < 16; ++u) {
                float a = (float)pa[u], c = (float)pc[u], b = (float)pB[u], dd = (float)pd[u];
                float vs_ = bs[d0 + u], vo_ = bo[d0 + u];
                s1 += a * c + a * vo_ + vs_ * c;
                s2 += b * dd + b * vo_ + vs_ * dd;
            }
            s1 = wave_reduce_sum(s1);
            s2 = wave_reduce_sum(s2);
            if (lane == 0) { nodeS[n] = s1; nodeO[n] = s2; }
        }
        return;
    }

    const __bf16* Ap = ACBD + (size_t)(z & 1) * 2 * Dd;
    const int ldA = 4 * Dd;
    const __bf16* Btp; int ldB, Nv, K; float* Of; int ldO;
    if (z == 0)      { Btp = ACBD + 3 * Dd; ldB = 4 * Dd; Nv = Nn; K = Dd;     Of = G_AD; ldO = Nn; }
    else if (z == 1) { Btp = ACBD + 1 * Dd; ldB = 4 * Dd; Nv = Nn; K = Dd;     Of = G_BC; ldO = Nn; }
    else             { Btp = KoKs;          ldB = 2 * Dd; Nv = Dd; K = 2 * Dd; Of = (z == 2) ? Pm : Qm; ldO = Dd; }
    const int m0 = blockIdx.x * 64, n0 = blockIdx.y * 64;
    if (m0 >= Nn || n0 >= Nv) return;

    __shared__ alignas(16) __bf16 As[64 * 64];
    __shared__ alignas(16) __bf16 Bs[64 * 64];
    const int t = threadIdx.x, lane = t & 63, wid = t >> 6;
    const int wm = wid >> 1, wn = wid & 1;
    const int rA = t >> 3;
    const int cSw = (t & 7) ^ (rA & 7);
    const int l15 = lane & 15;
    const int xorMask = (l15 & 7) << 4;
    v4f acc[2][2] = {};

    for (int kt = 0; kt < K; kt += 64) {
#pragma unroll
        for (int i = 0; i < 2; ++i)
            gload16(Ap + (size_t)(m0 + i * 32 + rA) * ldA + kt + cSw * 8,
                    (char*)As + i * 4096 + wid * 1024);
#pragma unroll
        for (int i = 0; i < 2; ++i)
            gload16(Btp + (size_t)(n0 + i * 32 + rA) * ldB + kt + cSw * 8,
                    (char*)Bs + i * 4096 + wid * 1024);
        __syncthreads();
#pragma unroll
        for (int ks = 0; ks < 2; ++ks) {
            const int kb = (ks * 64 + ((lane >> 4) << 4)) ^ xorMask;
            v8bf af[2], bfr[2];
#pragma unroll
            for (int f = 0; f < 2; ++f) {
                af[f]  = *(const v8bf*)((const char*)As + (wm * 32 + f * 16 + l15) * 128 + kb);
                bfr[f] = *(const v8bf*)((const char*)Bs + (wn * 32 + f * 16 + l15) * 128 + kb);
            }
#pragma unroll
            for (int i = 0; i < 2; ++i)
#pragma unroll
                for (int j = 0; j < 2; ++j)
                    acc[i][j] = __builtin_amdgcn_mfma_f32_16x16x32_bf16(af[i], bfr[j], acc[i][j], 0, 0, 0);
        }
        __syncthreads();
    }
    const int cc = lane & 15, r4 = (lane >> 4) << 2;
#pragma unroll
    for (int i = 0; i < 2; ++i)
#pragma unroll
        for (int j = 0; j < 2; ++j)
#pragma unroll
            for (int r = 0; r < 4; ++r) {
                const int gm = m0 + wm * 32 + i * 16 + r4 + r;
                const int gn = n0 + wn * 32 + j * 16 + cc;
                Of[(size_t)gm * ldO + gn] = acc[i][j][r];
            }
}

// ---------------- small custom kernels ----------------

__global__ __launch_bounds__(256) void edge_lmax_kernel(
    const float* __restrict__ q,
    const float* __restrict__ nodeS, const float* __restrict__ nodeO,
    const float* __restrict__ G_AD, const float* __restrict__ G_BC,
    const int* __restrict__ sbj, const int* __restrict__ obj,
    float* __restrict__ logits, unsigned* __restrict__ mS, unsigned* __restrict__ mO,
    int E, int Nn, float scale) {
    int e = blockIdx.x * 256 + threadIdx.x;
    if (e >= E) return;
    int s = sbj[e], o = obj[e];
    float l = (q[e] + nodeS[s] + nodeO[o] +
               G_AD[(size_t)s * Nn + o] + G_BC[(size_t)o * Nn + s]) * scale;
    logits[e] = l;
    unsigned k = fenc(l);
    atomicMax(mS + s, k);
    atomicMax(mO + o, k);
}

__global__ __launch_bounds__(256) void expsum_kernel(const float* __restrict__ logits,
                                                     const int* __restrict__ sbj,
                                                     const int* __restrict__ obj,
                                                     const unsigned* __restrict__ mS,
                                                     const unsigned* __restrict__ mO,
                                                     float* __restrict__ es, float* __restrict__ eo,
                                                     float* __restrict__ sumS, float* __restrict__ sumO,
                                                     int E) {
    int e = blockIdx.x * 256 + threadIdx.x;
    if (e >= E) return;
    float l = logits[e];
    int s = sbj[e], o = obj[e];
    float a = expf(l - fdec(mS[s]));
    es[e] = a;
    atomicAdd(sumS + s, a);
    float b = expf(l - fdec(mO[o]));
    eo[e] = b;
    atomicAdd(sumO + o, b);
}

__global__ __launch_bounds__(256) void scatter_kernel(const float* __restrict__ es,
                                                      const float* __restrict__ eo,
                                                      const float* __restrict__ sumS,
                                                      const float* __restrict__ sumO,
                                                      const int* __restrict__ sbj,
                                                      const int* __restrict__ obj,
                                                      float* __restrict__ S, int* __restrict__ inv,
                                                      int E, int Nn) {
    int e = blockIdx.x * 256 + threadIdx.x;
    if (e >= E) return;
    int s = sbj[e], o = obj[e];
    atomicAdd(S + (size_t)s * Nn + o, es[e] / sumS[s]);
    atomicAdd(S + (size_t)o * Nn + s, eo[e] / sumO[o]);
    inv[s] = 1;
    inv[o] = 1;
}

// ---------------- host launcher ----------------

extern "C" void kernel_launch(void* const* d_in, const int* in_sizes, int n_in,
                              void* d_out, int out_size, void* d_ws, size_t ws_size,
                              hipStream_t stream) {
    const float* V     = (const float*)d_in[0];
    const float* relv  = (const float*)d_in[1];
    const float* W_rel = (const float*)d_in[2];
    const float* b_rel = (const float*)d_in[3];
    const float* W_sbj = (const float*)d_in[4];
    const float* b_sbj = (const float*)d_in[5];
    const float* W_obj = (const float*)d_in[6];
    const float* b_obj = (const float*)d_in[7];
    const float* W_ctx = (const float*)d_in[8];
    const float* b_ctx = (const float*)d_in[9];
    const int* sbj = (const int*)d_in[10];
    const int* obj = (const int*)d_in[11];

    const int D  = in_sizes[3];
    const int E  = in_sizes[10];
    const int Nn = in_sizes[12];
    const size_t DD = (size_t)D * D;

    const float* Ws_r = W_sbj + DD;
    const float* Wo_r = W_obj + DD;

    char* ws = (char*)d_ws;
    size_t off = 0;
    auto alloc = [&](size_t bytes) -> void* {
        void* p = (void*)(ws + off);
        off += (bytes + 255) & ~(size_t)255;
        return p;
    };

    // persistent
    __bf16* relv_b = (__bf16*)alloc((size_t)E * D * 2);
    __bf16* Vb     = (__bf16*)alloc((size_t)Nn * D * 2);
    __bf16* VbT    = (__bf16*)alloc((size_t)D * Nn * 2);
    __bf16* ZT_b   = (__bf16*)alloc(DD * 2);
    __bf16* KoKs   = (__bf16*)alloc((size_t)D * 2 * D * 2);   // [D][2048] = [Ko | Ks]
    __bf16* ACBD   = (__bf16*)alloc((size_t)Nn * 4 * D * 2);  // [Nn][4D] = [A|C|B|D]
    __bf16* Ws_vT  = (__bf16*)alloc(DD * 2);
    __bf16* Wo_vT  = (__bf16*)alloc(DD * 2);
    __bf16* W_ctxT = (__bf16*)alloc(DD * 2);
    // region R1: Wr_all (3DD bf16) ... later G_AD+G_BC (2*Nn*Nn f32)
    size_t r1 = off;
    __bf16* Wr_all = (__bf16*)(ws + r1);
    float*  G_AD   = (float*)(ws + r1);
    float*  G_BC   = G_AD + (size_t)Nn * Nn;
    {
        size_t a = 3 * DD * 2, b = 2 * (size_t)Nn * Nn * 4;
        off += ((a > b ? a : b) + 255) & ~(size_t)255;
    }
    __bf16* WoWs_T = (__bf16*)alloc(2 * DD * 2);
    // region R3: MT_all (4DD bf16) ... later Pm+Qm
    size_t r3 = off;
    __bf16* MT_all = (__bf16*)(ws + r3);
    float*  Pm     = (float*)(ws + r3);
    float*  Qm     = Pm + (size_t)Nn * D;
    {
        size_t a = 4 * DD * 2, b = 2 * (size_t)Nn * D * 4;
        off += ((a > b ? a : b) + 255) & ~(size_t)255;
    }
    float* pb     = (float*)alloc((size_t)D * 4);
    float* nodeS  = (float*)alloc((size_t)Nn * 4);
    float* nodeO  = (float*)alloc((size_t)Nn * 4);
    float* logits = (float*)alloc((size_t)E * 4);
    float* es     = (float*)alloc((size_t)E * 4);
    float* eo     = (float*)alloc((size_t)E * 4);
    size_t zbeg = off;
    float* S      = (float*)alloc((size_t)Nn * Nn * 4);
    float* q      = (float*)alloc((size_t)E * 4);
    float* bs     = (float*)alloc((size_t)D * 4);
    float* bo     = (float*)alloc((size_t)D * 4);
    unsigned* mS  = (unsigned*)alloc((size_t)Nn * 4);
    unsigned* mO  = (unsigned*)alloc((size_t)Nn * 4);
    float* sumS   = (float*)alloc((size_t)Nn * 4);
    float* sumO   = (float*)alloc((size_t)Nn * 4);
    int* inv      = (int*)alloc((size_t)Nn * 4);
    size_t zend = off;
    __bf16* Sb    = (__bf16*)alloc((size_t)Nn * Nn * 2);
    __bf16* ctx_b = (__bf16*)alloc((size_t)Nn * D * 2);
    (void)ws_size; (void)n_in; (void)out_size;

    float* outVj = (float*)d_out + (size_t)E * D;

    // 1. zero atomic buffers (incl. bs/bo for megacvt's beta fold)
    hipMemsetAsync(ws + zbeg, 0, zend - zbeg, stream);

    // 2. megacvt: beta + six transposes FIRST (hide under the stream), then
    //    relv copy+cvt / W_rel cvt / V cvt at 32 B/thread with NT stores
    {
        long long nr = (long long)E * D, nw = 3 * (long long)DD, nv = (long long)Nn * D;
        long long NBs = (nr + nw + nv) / 8 / 256;
        long long total = 256 + 6LL * (D / 32) * (D / 32) + NBs;
        megacvt<<<dim3((unsigned)total), dim3(256), 0, stream>>>(
            relv, (float*)d_out, relv_b, nr, W_rel, Wr_all, nw, V, Vb, nv,
            b_rel, b_sbj, b_obj, Ws_r, Wo_r, bs, bo, D, Nn,
            WoWs_T, Ws_vT, Wo_vT, VbT, W_ctx, W_ctxT);
    }

    // 3. merged W-side precompute (384 blocks): MT_all quadrants + KoKs
    gemm_gl<5, true><<<dim3(24, 16), dim3(256), 0, stream>>>(
        WoWs_T, D, Wr_all, D, 3 * D, 2 * D, D, nullptr, 0, nullptr, MT_all, D,
        KoKs, Ws_vT, nullptr, nullptr, nullptr, nullptr, nullptr, Wo_vT);

    // 4. ZT = Ko@Ks^T  ||  ACBD = Vb@MT_all^T, one 128²-tile dispatch (z=2)
    gemm128_pair<<<dim3(8, 32, 2), dim3(256), 0, stream>>>(
        KoKs + 0, 2 * D, KoKs + D, 2 * D, D, D, ZT_b, D,
        Vb, D, MT_all, D, Nn, 4 * D, ACBD, 4 * D, D);

    // 5. penta: Grams + P/Q + (pbeta, node) in one dispatch (z=5)
    gemm64_penta<<<dim3(16, 16, 5), dim3(256), 0, stream>>>(
        ACBD, KoKs, G_AD, G_BC, Pm, Qm, bs, bo, pb, nodeS, nodeO, Nn, D);

    // 6. heavy: q[e] = (relv@Z).relv + relv.(Pm[s]+Qm[o]+pb)
    //    flat grid + chunked XCD swizzle for A-panel L2 reuse
    gemm_gl<3, true><<<dim3((E / 128) * (D / 128)), dim3(256), 0, stream>>>(
        relv_b, D, ZT_b, D, E, D, D, Pm, D, Qm, nullptr, 0, nullptr,
        relv_b, q, pb, nullptr, sbj, obj, nullptr);

    // 7-9. scalar logits + segment max, expsum, scatter
    edge_lmax_kernel<<<dim3(E / 256), dim3(256), 0, stream>>>(
        q, nodeS, nodeO, G_AD, G_BC, sbj, obj, logits, mS, mO, E, Nn, 1.0f / sqrtf((float)D));
    expsum_kernel<<<dim3(E / 256), dim3(256), 0, stream>>>(logits, sbj, obj, mS, mO, es, eo, sumS, sumO, E);
    scatter_kernel<<<dim3(E / 256), dim3(256), 0, stream>>>(es, eo, sumS, sumO, sbj, obj, S, inv, E, Nn);

    // 10. S -> bf16
    {
        size_t n = (size_t)Nn * Nn;
        cvt_f32_bf16<<<dim3((int)((n / 4 + 255) / 256)), dim3(256), 0, stream>>>(S, Sb, (long long)n);
    }
    // 11. ctx = S @ V
    gemm_gl<0, false><<<dim3(Nn / 64, D / 64), dim3(256), 0, stream>>>(
        Sb, Nn, VbT, Nn, Nn, D, Nn, nullptr, 0, nullptr, ctx_b, D,
        nullptr, nullptr, nullptr, nullptr, nullptr, nullptr, nullptr, nullptr);
    // 12. vj = V + mask * (ctx @ W_ctx + b_ctx)
    gemm_gl<4, false><<<dim3(Nn / 64, D / 64), dim3(256), 0, stream>>>(
        ctx_b, D, W_ctxT, D, Nn, D, D, V, D, outVj, nullptr, D,
        nullptr, nullptr, nullptr, b_ctx, inv, nullptr, nullptr, nullptr);
}

// Round 14
// 320.604 us; speedup vs baseline: 1.4185x; 1.0012x over previous
//
#include <hip/hip_runtime.h>
#include <hip/hip_bf16.h>
#include <math.h>
#include <type_traits>

typedef __bf16 v8bf __attribute__((ext_vector_type(8)));
typedef __bf16 v4bf __attribute__((ext_vector_type(4)));
typedef float  v4f  __attribute__((ext_vector_type(4)));

__device__ __forceinline__ float wave_reduce_sum(float v) {
#pragma unroll
    for (int m = 1; m < 64; m <<= 1) v += __shfl_xor(v, m, 64);
    return v;
}

__device__ __forceinline__ unsigned fenc(float x) {
    unsigned u = __float_as_uint(x);
    return (u & 0x80000000u) ? ~u : (u | 0x80000000u);
}
__device__ __forceinline__ float fdec(unsigned k) {
    return (k & 0x80000000u) ? __uint_as_float(k ^ 0x80000000u) : __uint_as_float(~k);
}

__device__ __forceinline__ void gload16(const void* g, void* l) {
    __builtin_amdgcn_global_load_lds((const __attribute__((address_space(1))) void*)g,
                                     (__attribute__((address_space(3))) void*)l, 16, 0, 0);
}

// ---------------- conversion kernels ----------------

__global__ __launch_bounds__(256) void cvt_f32_bf16(const float* __restrict__ in,
                                                    __bf16* __restrict__ out, long long n) {
    long long i = ((long long)blockIdx.x * 256 + threadIdx.x) * 4;
    if (i >= n) return;
    v4f v = *(const v4f*)(in + i);
    v4bf o;
    o[0] = (__bf16)v[0]; o[1] = (__bf16)v[1]; o[2] = (__bf16)v[2]; o[3] = (__bf16)v[3];
    *(v4bf*)(out + i) = o;
}

// Router grid (small latency-bound work FIRST so it hides under the stream):
//   blocks [0,256): beta (bs = b_sbj + b_rel@Ws_r ; bo = b_obj + b_rel@Wo_r)
//   blocks [256, 256+6*perz): six transpose-convert slices (32x32 tiles)
//   blocks [256+6*perz, ...): relv copy+cvt | W_rel cvt | V cvt, 8 floats/thread.
//   NT store ONLY for outCopy (write-once-never-read output 0 -> keeps L2/L3 clean
//   for relv_b which the heavy GEMM re-reads). relv_b uses a PLAIN store (R13's NT
//   on it cost ~20 us: megacvt 82->101 us).
__global__ __launch_bounds__(256) void megacvt(
    const float* __restrict__ relv, float* __restrict__ outCopy, __bf16* __restrict__ relv_b,
    long long nr,
    const float* __restrict__ wrel, __bf16* __restrict__ wrel_b, long long nw,
    const float* __restrict__ vsrc, __bf16* __restrict__ v_b, long long nv,
    const float* __restrict__ b_rel, const float* __restrict__ b_sbj, const float* __restrict__ b_obj,
    const float* __restrict__ Wsr, const float* __restrict__ Wor,
    float* __restrict__ bs, float* __restrict__ bo, int D, int Nn,
    __bf16* __restrict__ WoWs_T, __bf16* __restrict__ Ws_vT, __bf16* __restrict__ Wo_vT,
    __bf16* __restrict__ VbT, const float* __restrict__ W_ctx, __bf16* __restrict__ W_ctxT) {
    __shared__ float tile[32][33];
    const int perz = (D / 32) * (D / 32);
    const long long blk = blockIdx.x;
    const size_t DDl = (size_t)D * D;

    if (blk < 256) {
        // beta: 2-stage bias projection, coalesced row-major reads, atomicAdd partials
        int bb = (int)blk;
        const int col = (bb & 3) * 256 + threadIdx.x;
        const int chunk = (bb >> 2) & 31;
        const int mat = bb >> 7;
        const int rpc = D / 32;
        const int r0 = chunk * rpc;
        const float* W = (mat == 0) ? Wsr : Wor;
        float acc = 0.f;
        if (chunk == 0) acc = (mat == 0) ? b_sbj[col] : b_obj[col];
        for (int r = r0; r < r0 + rpc; ++r)
            acc += b_rel[r] * W[(size_t)r * D + col];
        atomicAdd(((mat == 0) ? bs : bo) + col, acc);
        return;
    }
    if (blk < 256 + 6LL * perz) {
        int tb = (int)(blk - 256);
        int z = tb / perz, rem = tb % perz;
        const float* ins[6];
        __bf16* outs[6];
        int Rs[6];
        ins[0] = Wor;        outs[0] = WoWs_T;       Rs[0] = D;   // Wo_r^T
        ins[1] = Wsr;        outs[1] = WoWs_T + DDl; Rs[1] = D;   // Ws_r^T
        ins[2] = Wsr - DDl;  outs[2] = Ws_vT;        Rs[2] = D;   // Ws_v^T (= W_sbj[:D])
        ins[3] = Wor - DDl;  outs[3] = Wo_vT;        Rs[3] = D;   // Wo_v^T (= W_obj[:D])
        ins[4] = vsrc;       outs[4] = VbT;          Rs[4] = Nn;  // V^T
        ins[5] = W_ctx;      outs[5] = W_ctxT;       Rs[5] = D;   // W_ctx^T
        const float* in = ins[z];
        __bf16* out = outs[z];
        const int R = Rs[z], C = D;
        int cb = (rem % (D / 32)) * 32, rb = (rem / (D / 32)) * 32;
        if (cb >= C || rb >= R) return;
        int tx = threadIdx.x & 31, ty = threadIdx.x >> 5;
#pragma unroll
        for (int i = 0; i < 32; i += 8)
            tile[ty + i][tx] = in[(size_t)(rb + ty + i) * C + cb + tx];
        __syncthreads();
#pragma unroll
        for (int i = 0; i < 32; i += 8)
            out[(size_t)(cb + ty + i) * R + rb + tx] = (__bf16)tile[tx][ty + i];
        return;
    }
    // stream: 8 floats per thread
    long long i = ((blk - 256 - 6LL * perz) * 256 + threadIdx.x) * 8;
    if (i < nr) {
        v4f a = *(const v4f*)(relv + i);
        v4f b = *(const v4f*)(relv + i + 4);
        __builtin_nontemporal_store(a, (v4f*)(outCopy + i));
        __builtin_nontemporal_store(b, (v4f*)(outCopy + i + 4));
        v8bf o;
        o[0] = (__bf16)a[0]; o[1] = (__bf16)a[1]; o[2] = (__bf16)a[2]; o[3] = (__bf16)a[3];
        o[4] = (__bf16)b[0]; o[5] = (__bf16)b[1]; o[6] = (__bf16)b[2]; o[7] = (__bf16)b[3];
        *(v8bf*)(relv_b + i) = o;   // plain store: re-read by heavy GEMM, keep cacheable
    } else if (i < nr + nw) {
        long long j = i - nr;
        v4f a = *(const v4f*)(wrel + j);
        v4f b = *(const v4f*)(wrel + j + 4);
        v8bf o;
        o[0] = (__bf16)a[0]; o[1] = (__bf16)a[1]; o[2] = (__bf16)a[2]; o[3] = (__bf16)a[3];
        o[4] = (__bf16)b[0]; o[5] = (__bf16)b[1]; o[6] = (__bf16)b[2]; o[7] = (__bf16)b[3];
        *(v8bf*)(wrel_b + j) = o;
    } else if (i < nr + nw + nv) {
        long long j = i - nr - nw;
        v4f a = *(const v4f*)(vsrc + j);
        v4f b = *(const v4f*)(vsrc + j + 4);
        v8bf o;
        o[0] = (__bf16)a[0]; o[1] = (__bf16)a[1]; o[2] = (__bf16)a[2]; o[3] = (__bf16)a[3];
        o[4] = (__bf16)b[0]; o[5] = (__bf16)b[1]; o[6] = (__bf16)b[2]; o[7] = (__bf16)b[3];
        *(v8bf*)(v_b + j) = o;
    }
}

// ---- bf16 MFMA GEMM, m97 structure + XOR-swizzled LDS ----
// __launch_bounds__(256, 4): VGPR 64, no spill (R12's (256,5) clamped VGPR to 48 ->
// 160 MB scratch spill traffic, heavy 81->160 us. Do not raise past 4.)
// MODE 0: outB (bf16, plain, ldOut) = acc (+addMat f32 [ldAdd] if non-null)
// MODE 3: fused logits partial (flat grid + chunked XCD swizzle)
// MODE 4: outF[m][n] = addMat[m][n] + (maskRow[m] ? acc + addRow[n] : 0)
// MODE 5: merged W-side: m-blocks 0-1 -> MT quadrants; m-block 2 -> KoKs.
template <int MODE, bool BIG>
__global__ __launch_bounds__(256, 4) void gemm_gl(
    const __bf16* __restrict__ Ap, int ldA,
    const __bf16* __restrict__ Btp, int ldB,
    int M, int N, int K,
    const float* __restrict__ addMat, int ldAdd,
    float* __restrict__ outF,
    __bf16* __restrict__ outB, int ldOut,
    __bf16* __restrict__ outB2,
    const __bf16* __restrict__ rbDot,
    float* __restrict__ qOut,
    const float* __restrict__ addRow,
    const int* __restrict__ maskRow,
    const int* __restrict__ sbjI,
    const int* __restrict__ objI,
    const __bf16* __restrict__ auxW) {
    constexpr int BM = BIG ? 128 : 64;
    constexpr int BN = BIG ? 128 : 64;
    constexpr int WM = BM / 2, WN = BN / 2;
    constexpr int FI = WM / 16, FJ = WN / 16;
    constexpr int NLA = (BM * 64) / 2048;
    constexpr int NLB = (BN * 64) / 2048;

    __shared__ alignas(16) __bf16 As[BM * 64];
    __shared__ alignas(16) __bf16 Bs[BN * 64];

    int m0, n0;
    if constexpr (MODE == 3) {
        // flat grid, chunked XCD swizzle: id%8 = mb%8 (panel pinned to one XCD);
        // the panel's 8 n-blocks are 8 ids apart -> temporally adjacent -> L2 reuse.
        const int id = blockIdx.x;
        const int mb = (id >> 6) * 8 + (id & 7);
        const int nb = (id >> 3) & 7;
        m0 = mb * BM;
        n0 = nb * BN;
    } else {
        m0 = blockIdx.x * BM;
        n0 = blockIdx.y * BN;
    }
    bool kRows = false;
    if constexpr (MODE == 5) {
        if (m0 >= 2048) {  // KoKs rows: A = Wr_r (= Btp + 2*K*K), Bt = WoWs_T (= Ap)
            kRows = true;
            const __bf16* t = Ap;
            Ap = Btp + (size_t)2 * K * K;
            Btp = t;
            m0 -= 2048;
        }
    }

    const int t = threadIdx.x, lane = t & 63, wid = t >> 6;
    const int wm = wid >> 1, wn = wid & 1;
    const int rA = t >> 3;
    const int cSw = (t & 7) ^ (rA & 7);            // swizzled 16B-chunk (involution)

    v4f acc[FI][FJ] = {};

    const int l15 = lane & 15;
    const int xorMask = (l15 & 7) << 4;            // read-side XOR (bytes)

    for (int kt = 0; kt < K; kt += 64) {
#pragma unroll
        for (int i = 0; i < NLA; ++i)
            gload16(Ap + (size_t)(m0 + i * 32 + rA) * ldA + kt + cSw * 8,
                    (char*)As + i * 4096 + wid * 1024);
#pragma unroll
        for (int i = 0; i < NLB; ++i)
            gload16(Btp + (size_t)(n0 + i * 32 + rA) * ldB + kt + cSw * 8,
                    (char*)Bs + i * 4096 + wid * 1024);
        __syncthreads();
#pragma unroll
        for (int ks = 0; ks < 2; ++ks) {
            const int kb = (ks * 64 + ((lane >> 4) << 4)) ^ xorMask;
            v8bf af[FI], bfr[FJ];
#pragma unroll
            for (int f = 0; f < FI; ++f)
                af[f] = *(const v8bf*)((const char*)As + (wm * WM + f * 16 + l15) * 128 + kb);
#pragma unroll
            for (int f = 0; f < FJ; ++f)
                bfr[f] = *(const v8bf*)((const char*)Bs + (wn * WN + f * 16 + l15) * 128 + kb);
#pragma unroll
            for (int i = 0; i < FI; ++i)
#pragma unroll
                for (int j = 0; j < FJ; ++j)
                    acc[i][j] = __builtin_amdgcn_mfma_f32_16x16x32_bf16(af[i], bfr[j], acc[i][j], 0, 0, 0);
        }
        __syncthreads();
    }

    const int cc = lane & 15, r4 = (lane >> 4) << 2;
    if constexpr (MODE == 3) {
#pragma unroll
        for (int i = 0; i < FI; ++i)
#pragma unroll
            for (int r = 0; r < 4; ++r) {
                const int gm = m0 + wm * WM + i * 16 + r4 + r;
                const int s = sbjI[gm], o = objI[gm];
                const float* Ps = addMat + (size_t)s * ldAdd;
                const float* Qo = outF + (size_t)o * ldAdd;
                float p = 0.f;
#pragma unroll
                for (int j = 0; j < FJ; ++j) {
                    const int gn = n0 + wn * WN + j * 16 + cc;
                    float rv = (float)rbDot[(size_t)gm * N + gn];
                    p += rv * (acc[i][j][r] + Ps[gn] + Qo[gn] + addRow[gn]);
                }
                p += __shfl_xor(p, 1, 64);
                p += __shfl_xor(p, 2, 64);
                p += __shfl_xor(p, 4, 64);
                p += __shfl_xor(p, 8, 64);
                if (cc == 0) atomicAdd(qOut + gm, p);
            }
    } else if constexpr (MODE == 5) {
        if (kRows) {
#pragma unroll
            for (int i = 0; i < FI; ++i)
#pragma unroll
                for (int j = 0; j < FJ; ++j)
#pragma unroll
                    for (int r = 0; r < 4; ++r) {
                        const int gm = m0 + wm * WM + i * 16 + r4 + r;
                        const int gn = n0 + wn * WN + j * 16 + cc;
                        outB2[(size_t)gm * 2048 + gn] = (__bf16)acc[i][j][r];
                    }
        } else {
            const int mb = m0 >> 10, nb = n0 >> 10;
            const int blk = (mb == 0) ? (nb ? 3 : 1) : (nb ? 2 : 0);
            const __bf16* addB = (blk == 0) ? rbDot : (blk == 3 ? auxW : nullptr);
            const size_t DDe = (size_t)ldOut * ldOut;
            __bf16* dst = outB + (size_t)blk * DDe;
#pragma unroll
            for (int i = 0; i < FI; ++i)
#pragma unroll
                for (int j = 0; j < FJ; ++j)
#pragma unroll
                    for (int r = 0; r < 4; ++r) {
                        const int gml = (m0 + wm * WM + i * 16 + r4 + r) & 1023;
                        const int gnl = (n0 + wn * WN + j * 16 + cc) & 1023;
                        float v = acc[i][j][r];
                        if (addB) v += (float)addB[(size_t)gml * ldOut + gnl];
                        dst[(size_t)gml * ldOut + gnl] = (__bf16)v;
                    }
        }
    } else {
#pragma unroll
        for (int i = 0; i < FI; ++i)
#pragma unroll
            for (int j = 0; j < FJ; ++j)
#pragma unroll
                for (int r = 0; r < 4; ++r) {
                    const int gm = m0 + wm * WM + i * 16 + r4 + r;
                    const int gn = n0 + wn * WN + j * 16 + cc;
                    float v = acc[i][j][r];
                    if constexpr (MODE == 0) {
                        if (addMat) v += addMat[(size_t)gm * ldAdd + gn];
                        outB[(size_t)gm * ldOut + gn] = (__bf16)v;
                    } else {  // MODE 4
                        float u = addMat[(size_t)gm * ldAdd + gn];
                        if (maskRow[gm]) u += v + addRow[gn];
                        outF[(size_t)gm * ldOut + gn] = u;
                    }
                }
    }
}

// ---- batched pair at 128² tiles: z=0 ZT = Ko@Ks^T ; z=1 ACBD = Vb@MT_all^T ----
__global__ __launch_bounds__(256, 4) void gemm128_pair(
    const __bf16* __restrict__ A0, int ldA0, const __bf16* __restrict__ B0, int ldB0,
    int M0v, int N0v, __bf16* __restrict__ O0, int ldO0,
    const __bf16* __restrict__ A1, int ldA1, const __bf16* __restrict__ B1, int ldB1,
    int M1v, int N1v, __bf16* __restrict__ O1, int ldO1, int K) {
    const __bf16* Ap; const __bf16* Btp; __bf16* Ob;
    int ldA, ldB, Mv, Nv, ldO;
    if (blockIdx.z == 0) { Ap = A0; Btp = B0; Ob = O0; ldA = ldA0; ldB = ldB0; Mv = M0v; Nv = N0v; ldO = ldO0; }
    else                 { Ap = A1; Btp = B1; Ob = O1; ldA = ldA1; ldB = ldB1; Mv = M1v; Nv = N1v; ldO = ldO1; }
    const int m0 = blockIdx.x * 128, n0 = blockIdx.y * 128;
    if (m0 >= Mv || n0 >= Nv) return;

    __shared__ alignas(16) __bf16 As[128 * 64];
    __shared__ alignas(16) __bf16 Bs[128 * 64];
    const int t = threadIdx.x, lane = t & 63, wid = t >> 6;
    const int wm = wid >> 1, wn = wid & 1;
    const int rA = t >> 3;
    const int cSw = (t & 7) ^ (rA & 7);
    const int l15 = lane & 15;
    const int xorMask = (l15 & 7) << 4;
    v4f acc[4][4] = {};

    for (int kt = 0; kt < K; kt += 64) {
#pragma unroll
        for (int i = 0; i < 4; ++i)
            gload16(Ap + (size_t)(m0 + i * 32 + rA) * ldA + kt + cSw * 8,
                    (char*)As + i * 4096 + wid * 1024);
#pragma unroll
        for (int i = 0; i < 4; ++i)
            gload16(Btp + (size_t)(n0 + i * 32 + rA) * ldB + kt + cSw * 8,
                    (char*)Bs + i * 4096 + wid * 1024);
        __syncthreads();
#pragma unroll
        for (int ks = 0; ks < 2; ++ks) {
            const int kb = (ks * 64 + ((lane >> 4) << 4)) ^ xorMask;
            v8bf af[4], bfr[4];
#pragma unroll
            for (int f = 0; f < 4; ++f) {
                af[f]  = *(const v8bf*)((const char*)As + (wm * 64 + f * 16 + l15) * 128 + kb);
                bfr[f] = *(const v8bf*)((const char*)Bs + (wn * 64 + f * 16 + l15) * 128 + kb);
            }
#pragma unroll
            for (int i = 0; i < 4; ++i)
#pragma unroll
                for (int j = 0; j < 4; ++j)
                    acc[i][j] = __builtin_amdgcn_mfma_f32_16x16x32_bf16(af[i], bfr[j], acc[i][j], 0, 0, 0);
        }
        __syncthreads();
    }
    const int cc = lane & 15, r4 = (lane >> 4) << 2;
#pragma unroll
    for (int i = 0; i < 4; ++i)
#pragma unroll
        for (int j = 0; j < 4; ++j)
#pragma unroll
            for (int r = 0; r < 4; ++r) {
                const int gm = m0 + wm * 64 + i * 16 + r4 + r;
                const int gn = n0 + wn * 64 + j * 16 + cc;
                Ob[(size_t)gm * ldO + gn] = (__bf16)acc[i][j][r];
            }
}

// ---- penta: z0 G_AD=A@D^T, z1 G_BC=B@C^T (K=D), z2 Pm, z3 Qm (K=2D),
//      z4: aux slice — pbeta rows + node terms ----
__global__ __launch_bounds__(256, 4) void gemm64_penta(
    const __bf16* __restrict__ ACBD, const __bf16* __restrict__ KoKs,
    float* __restrict__ G_AD, float* __restrict__ G_BC,
    float* __restrict__ Pm, float* __restrict__ Qm,
    const float* __restrict__ bs, const float* __restrict__ bo,
    float* __restrict__ pb, float* __restrict__ nodeS, float* __restrict__ nodeO,
    int Nn, int Dd) {
    const int z = blockIdx.z;
    if (z == 4) {
        const int bb = blockIdx.y * 16 + blockIdx.x;
        const int w = threadIdx.x >> 6, lane = threadIdx.x & 63;
        {
            const int d = bb * 4 + w;
            float a = 0.f;
            for (int j = lane; j < Dd; j += 64)
                a += bs[j] * (float)KoKs[(size_t)d * 2048 + j] +
                     bo[j] * (float)KoKs[(size_t)d * 2048 + 1024 + j];
            a = wave_reduce_sum(a);
            if (lane == 0) pb[d] = a;
        }
        if (bb * 4 + w < Nn) {
            const int n = bb * 4 + w;
            const int d0 = lane * 16;
            const __bf16* row = ACBD + (size_t)n * 4 * Dd;
            const __bf16* pa = row + d0;
            const __bf16* pc = row + Dd + d0;
            const __bf16* pB = row + 2 * Dd + d0;
            const __bf16* pd = row + 3 * Dd + d0;
            float s1 = 0.f, s2 = 0.f;
#pragma unroll
            for (int u = 0; u < 16; ++u) {
                float a = (float)pa[u], c = (float)pc[u], b = (float)pB[u], dd = (float)pd[u];
                float vs_ = bs[d0 + u], vo_ = bo[d0 + u];
                s1 += a * c + a * vo_ + vs_ * c;
                s2 += b * dd + b * vo_ + vs_ * dd;
            }
            s1 = wave_reduce_sum(s1);
            s2 = wave_reduce_sum(s2);
            if (lane == 0) { nodeS[n] = s1; nodeO[n] = s2; }
        }
        return;
    }

    const __bf16* Ap = ACBD + (size_t)(z & 1) * 2 * Dd;
    const int ldA = 4 * Dd;
    const __bf16* Btp; int ldB, Nv, K; float* Of; int ldO;
    if (z == 0)      { Btp = ACBD + 3 * Dd; ldB = 4 * Dd; Nv = Nn; K = Dd;     Of = G_AD; ldO = Nn; }
    else if (z == 1) { Btp = ACBD + 1 * Dd; ldB = 4 * Dd; Nv = Nn; K = Dd;     Of = G_BC; ldO = Nn; }
    else             { Btp = KoKs;          ldB = 2 * Dd; Nv = Dd; K = 2 * Dd; Of = (z == 2) ? Pm : Qm; ldO = Dd; }
    const int m0 = blockIdx.x * 64, n0 = blockIdx.y * 64;
    if (m0 >= Nn || n0 >= Nv) return;

    __shared__ alignas(16) __bf16 As[64 * 64];
    __shared__ alignas(16) __bf16 Bs[64 * 64];
    const int t = threadIdx.x, lane = t & 63, wid = t >> 6;
    const int wm = wid >> 1, wn = wid & 1;
    const int rA = t >> 3;
    const int cSw = (t & 7) ^ (rA & 7);
    const int l15 = lane & 15;
    const int xorMask = (l15 & 7) << 4;
    v4f acc[2][2] = {};

    for (int kt = 0; kt < K; kt += 64) {
#pragma unroll
        for (int i = 0; i < 2; ++i)
            gload16(Ap + (size_t)(m0 + i * 32 + rA) * ldA + kt + cSw * 8,
                    (char*)As + i * 4096 + wid * 1024);
#pragma unroll
        for (int i = 0; i < 2; ++i)
            gload16(Btp + (size_t)(n0 + i * 32 + rA) * ldB + kt + cSw * 8,
                    (char*)Bs + i * 4096 + wid * 1024);
        __syncthreads();
#pragma unroll
        for (int ks = 0; ks < 2; ++ks) {
            const int kb = (ks * 64 + ((lane >> 4) << 4)) ^ xorMask;
            v8bf af[2], bfr[2];
#pragma unroll
            for (int f = 0; f < 2; ++f) {
                af[f]  = *(const v8bf*)((const char*)As + (wm * 32 + f * 16 + l15) * 128 + kb);
                bfr[f] = *(const v8bf*)((const char*)Bs + (wn * 32 + f * 16 + l15) * 128 + kb);
            }
#pragma unroll
            for (int i = 0; i < 2; ++i)
#pragma unroll
                for (int j = 0; j < 2; ++j)
                    acc[i][j] = __builtin_amdgcn_mfma_f32_16x16x32_bf16(af[i], bfr[j], acc[i][j], 0, 0, 0);
        }
        __syncthreads();
    }
    const int cc = lane & 15, r4 = (lane >> 4) << 2;
#pragma unroll
    for (int i = 0; i < 2; ++i)
#pragma unroll
        for (int j = 0; j < 2; ++j)
#pragma unroll
            for (int r = 0; r < 4; ++r) {
                const int gm = m0 + wm * 32 + i * 16 + r4 + r;
                const int gn = n0 + wn * 32 + j * 16 + cc;
                Of[(size_t)gm * ldO + gn] = acc[i][j][r];
            }
}

// ---------------- small custom kernels ----------------

__global__ __launch_bounds__(256) void edge_lmax_kernel(
    const float* __restrict__ q,
    const float* __restrict__ nodeS, const float* __restrict__ nodeO,
    const float* __restrict__ G_AD, const float* __restrict__ G_BC,
    const int* __restrict__ sbj, const int* __restrict__ obj,
    float* __restrict__ logits, unsigned* __restrict__ mS, unsigned* __restrict__ mO,
    int E, int Nn, float scale) {
    int e = blockIdx.x * 256 + threadIdx.x;
    if (e >= E) return;
    int s = sbj[e], o = obj[e];
    float l = (q[e] + nodeS[s] + nodeO[o] +
               G_AD[(size_t)s * Nn + o] + G_BC[(size_t)o * Nn + s]) * scale;
    logits[e] = l;
    unsigned k = fenc(l);
    atomicMax(mS + s, k);
    atomicMax(mO + o, k);
}

__global__ __launch_bounds__(256) void expsum_kernel(const float* __restrict__ logits,
                                                     const int* __restrict__ sbj,
                                                     const int* __restrict__ obj,
                                                     const unsigned* __restrict__ mS,
                                                     const unsigned* __restrict__ mO,
                                                     float* __restrict__ es, float* __restrict__ eo,
                                                     float* __restrict__ sumS, float* __restrict__ sumO,
                                                     int E) {
    int e = blockIdx.x * 256 + threadIdx.x;
    if (e >= E) return;
    float l = logits[e];
    int s = sbj[e], o = obj[e];
    float a = expf(l - fdec(mS[s]));
    es[e] = a;
    atomicAdd(sumS + s, a);
    float b = expf(l - fdec(mO[o]));
    eo[e] = b;
    atomicAdd(sumO + o, b);
}

__global__ __launch_bounds__(256) void scatter_kernel(const float* __restrict__ es,
                                                      const float* __restrict__ eo,
                                                      const float* __restrict__ sumS,
                                                      const float* __restrict__ sumO,
                                                      const int* __restrict__ sbj,
                                                      const int* __restrict__ obj,
                                                      float* __restrict__ S, int* __restrict__ inv,
                                                      int E, int Nn) {
    int e = blockIdx.x * 256 + threadIdx.x;
    if (e >= E) return;
    int s = sbj[e], o = obj[e];
    atomicAdd(S + (size_t)s * Nn + o, es[e] / sumS[s]);
    atomicAdd(S + (size_t)o * Nn + s, eo[e] / sumO[o]);
    inv[s] = 1;
    inv[o] = 1;
}

// ---------------- host launcher ----------------

extern "C" void kernel_launch(void* const* d_in, const int* in_sizes, int n_in,
                              void* d_out, int out_size, void* d_ws, size_t ws_size,
                              hipStream_t stream) {
    const float* V     = (const float*)d_in[0];
    const float* relv  = (const float*)d_in[1];
    const float* W_rel = (const float*)d_in[2];
    const float* b_rel = (const float*)d_in[3];
    const float* W_sbj = (const float*)d_in[4];
    const float* b_sbj = (const float*)d_in[5];
    const float* W_obj = (const float*)d_in[6];
    const float* b_obj = (const float*)d_in[7];
    const float* W_ctx = (const float*)d_in[8];
    const float* b_ctx = (const float*)d_in[9];
    const int* sbj = (const int*)d_in[10];
    const int* obj = (const int*)d_in[11];

    const int D  = in_sizes[3];
    const int E  = in_sizes[10];
    const int Nn = in_sizes[12];
    const size_t DD = (size_t)D * D;

    const float* Ws_r = W_sbj + DD;
    const float* Wo_r = W_obj + DD;

    char* ws = (char*)d_ws;
    size_t off = 0;
    auto alloc = [&](size_t bytes) -> void* {
        void* p = (void*)(ws + off);
        off += (bytes + 255) & ~(size_t)255;
        return p;
    };

    // persistent
    __bf16* relv_b = (__bf16*)alloc((size_t)E * D * 2);
    __bf16* Vb     = (__bf16*)alloc((size_t)Nn * D * 2);
    __bf16* VbT    = (__bf16*)alloc((size_t)D * Nn * 2);
    __bf16* ZT_b   = (__bf16*)alloc(DD * 2);
    __bf16* KoKs   = (__bf16*)alloc((size_t)D * 2 * D * 2);   // [D][2048] = [Ko | Ks]
    __bf16* ACBD   = (__bf16*)alloc((size_t)Nn * 4 * D * 2);  // [Nn][4D] = [A|C|B|D]
    __bf16* Ws_vT  = (__bf16*)alloc(DD * 2);
    __bf16* Wo_vT  = (__bf16*)alloc(DD * 2);
    __bf16* W_ctxT = (__bf16*)alloc(DD * 2);
    // region R1: Wr_all (3DD bf16) ... later G_AD+G_BC (2*Nn*Nn f32)
    size_t r1 = off;
    __bf16* Wr_all = (__bf16*)(ws + r1);
    float*  G_AD   = (float*)(ws + r1);
    float*  G_BC   = G_AD + (size_t)Nn * Nn;
    {
        size_t a = 3 * DD * 2, b = 2 * (size_t)Nn * Nn * 4;
        off += ((a > b ? a : b) + 255) & ~(size_t)255;
    }
    __bf16* WoWs_T = (__bf16*)alloc(2 * DD * 2);
    // region R3: MT_all (4DD bf16) ... later Pm+Qm
    size_t r3 = off;
    __bf16* MT_all = (__bf16*)(ws + r3);
    float*  Pm     = (float*)(ws + r3);
    float*  Qm     = Pm + (size_t)Nn * D;
    {
        size_t a = 4 * DD * 2, b = 2 * (size_t)Nn * D * 4;
        off += ((a > b ? a : b) + 255) & ~(size_t)255;
    }
    float* pb     = (float*)alloc((size_t)D * 4);
    float* nodeS  = (float*)alloc((size_t)Nn * 4);
    float* nodeO  = (float*)alloc((size_t)Nn * 4);
    float* logits = (float*)alloc((size_t)E * 4);
    float* es     = (float*)alloc((size_t)E * 4);
    float* eo     = (float*)alloc((size_t)E * 4);
    size_t zbeg = off;
    float* S      = (float*)alloc((size_t)Nn * Nn * 4);
    float* q      = (float*)alloc((size_t)E * 4);
    float* bs     = (float*)alloc((size_t)D * 4);
    float* bo     = (float*)alloc((size_t)D * 4);
    unsigned* mS  = (unsigned*)alloc((size_t)Nn * 4);
    unsigned* mO  = (unsigned*)alloc((size_t)Nn * 4);
    float* sumS   = (float*)alloc((size_t)Nn * 4);
    float* sumO   = (float*)alloc((size_t)Nn * 4);
    int* inv      = (int*)alloc((size_t)Nn * 4);
    size_t zend = off;
    __bf16* Sb    = (__bf16*)alloc((size_t)Nn * Nn * 2);
    __bf16* ctx_b = (__bf16*)alloc((size_t)Nn * D * 2);
    (void)ws_size; (void)n_in; (void)out_size;

    float* outVj = (float*)d_out + (size_t)E * D;

    // 1. zero atomic buffers (incl. bs/bo for megacvt's beta fold)
    hipMemsetAsync(ws + zbeg, 0, zend - zbeg, stream);

    // 2. megacvt: beta + six transposes FIRST, then the big stream
    {
        long long nr = (long long)E * D, nw = 3 * (long long)DD, nv = (long long)Nn * D;
        long long NBs = (nr + nw + nv) / 8 / 256;
        long long total = 256 + 6LL * (D / 32) * (D / 32) + NBs;
        megacvt<<<dim3((unsigned)total), dim3(256), 0, stream>>>(
            relv, (float*)d_out, relv_b, nr, W_rel, Wr_all, nw, V, Vb, nv,
            b_rel, b_sbj, b_obj, Ws_r, Wo_r, bs, bo, D, Nn,
            WoWs_T, Ws_vT, Wo_vT, VbT, W_ctx, W_ctxT);
    }

    // 3. merged W-side precompute (384 blocks): MT_all quadrants + KoKs
    gemm_gl<5, true><<<dim3(24, 16), dim3(256), 0, stream>>>(
        WoWs_T, D, Wr_all, D, 3 * D, 2 * D, D, nullptr, 0, nullptr, MT_all, D,
        KoKs, Ws_vT, nullptr, nullptr, nullptr, nullptr, nullptr, Wo_vT);

    // 4. ZT = Ko@Ks^T  ||  ACBD = Vb@MT_all^T, one 128²-tile dispatch (z=2)
    gemm128_pair<<<dim3(8, 32, 2), dim3(256), 0, stream>>>(
        KoKs + 0, 2 * D, KoKs + D, 2 * D, D, D, ZT_b, D,
        Vb, D, MT_all, D, Nn, 4 * D, ACBD, 4 * D, D);

    // 5. penta: Grams + P/Q + (pbeta, node) in one dispatch (z=5)
    gemm64_penta<<<dim3(16, 16, 5), dim3(256), 0, stream>>>(
        ACBD, KoKs, G_AD, G_BC, Pm, Qm, bs, bo, pb, nodeS, nodeO, Nn, D);

    // 6. heavy: q[e] = (relv@Z).relv + relv.(Pm[s]+Qm[o]+pb)
    //    flat grid + chunked XCD swizzle for A-panel L2 reuse
    gemm_gl<3, true><<<dim3((E / 128) * (D / 128)), dim3(256), 0, stream>>>(
        relv_b, D, ZT_b, D, E, D, D, Pm, D, Qm, nullptr, 0, nullptr,
        relv_b, q, pb, nullptr, sbj, obj, nullptr);

    // 7-9. scalar logits + segment max, expsum, scatter
    edge_lmax_kernel<<<dim3(E / 256), dim3(256), 0, stream>>>(
        q, nodeS, nodeO, G_AD, G_BC, sbj, obj, logits, mS, mO, E, Nn, 1.0f / sqrtf((float)D));
    expsum_kernel<<<dim3(E / 256), dim3(256), 0, stream>>>(logits, sbj, obj, mS, mO, es, eo, sumS, sumO, E);
    scatter_kernel<<<dim3(E / 256), dim3(256), 0, stream>>>(es, eo, sumS, sumO, sbj, obj, S, inv, E, Nn);

    // 10. S -> bf16
    {
        size_t n = (size_t)Nn * Nn;
        cvt_f32_bf16<<<dim3((int)((n / 4 + 255) / 256)), dim3(256), 0, stream>>>(S, Sb, (long long)n);
    }
    // 11. ctx = S @ V
    gemm_gl<0, false><<<dim3(Nn / 64, D / 64), dim3(256), 0, stream>>>(
        Sb, Nn, VbT, Nn, Nn, D, Nn, nullptr, 0, nullptr, ctx_b, D,
        nullptr, nullptr, nullptr, nullptr, nullptr, nullptr, nullptr, nullptr);
    // 12. vj = V + mask * (ctx @ W_ctx + b_ctx)
    gemm_gl<4, false><<<dim3(Nn / 64, D / 64), dim3(256), 0, stream>>>(
        ctx_b, D, W_ctxT, D, Nn, D, D, V, D, outVj, nullptr, D,
        nullptr, nullptr, nullptr, b_ctx, inv, nullptr, nullptr, nullptr);
}